// Round 2
// baseline (1161.870 us; speedup 1.0000x reference)
//
#include <hip/hip_runtime.h>

#define DIN 128
#define HEADS 4
#define CPH 32
#define NEG_SLOPE 0.2f
#define LN_EPS 1e-5f

// block of 128 threads (2 waves) sum
__device__ __forceinline__ float block_sum_128(float v, float* tmp2) {
#pragma unroll
    for (int off = 32; off > 0; off >>= 1) v += __shfl_down(v, off, 64);
    int lane = threadIdx.x & 63, wid = threadIdx.x >> 6;
    if (lane == 0) tmp2[wid] = v;
    __syncthreads();
    float r = tmp2[0] + tmp2[1];
    __syncthreads();
    return r;
}

// monotonic float->uint mapping for atomicMax on floats; 0u maps below all finite values
__device__ __forceinline__ unsigned int fmap(float f) {
    unsigned int b = __float_as_uint(f);
    return (b & 0x80000000u) ? ~b : (b | 0x80000000u);
}
__device__ __forceinline__ float funmap(unsigned int m) {
    return (m & 0x80000000u) ? __uint_as_float(m & 0x7FFFFFFFu) : __uint_as_float(~m);
}

// ---------- K1: LN1 + projection + attention logits ----------
__global__ __launch_bounds__(128) void k_ln_proj(
    const float* __restrict__ x,
    const float* __restrict__ g1, const float* __restrict__ b1,
    const float* __restrict__ W,
    const float* __restrict__ att_src, const float* __restrict__ att_dst,
    float* __restrict__ xh, float* __restrict__ a_src, float* __restrict__ a_dst, int N)
{
    int n = blockIdx.x, t = threadIdx.x;
    __shared__ float sh[DIN];
    __shared__ float sa[DIN];
    __shared__ float sb[DIN];
    __shared__ float tmp2[2];

    float xv = x[n * DIN + t];
    float mean = block_sum_128(xv, tmp2) * (1.0f / DIN);
    float d = xv - mean;
    float var = block_sum_128(d * d, tmp2) * (1.0f / DIN);
    float hn = d * rsqrtf(var + LN_EPS) * g1[t] + b1[t];
    sh[t] = hn;
    __syncthreads();

    float acc = 0.0f;
#pragma unroll 8
    for (int k = 0; k < DIN; ++k)
        acc += sh[k] * W[k * DIN + t];
    xh[n * DIN + t] = acc;

    sa[t] = acc * att_src[t];
    sb[t] = acc * att_dst[t];
    __syncthreads();
    if (t < HEADS) {
        float s1 = 0.f, s2 = 0.f;
#pragma unroll
        for (int i = 0; i < CPH; ++i) { s1 += sa[t * CPH + i]; s2 += sb[t * CPH + i]; }
        a_src[n * HEADS + t] = s1;
        a_dst[n * HEADS + t] = s2;
    }
}

// ---------- K2: segment max over dst ----------
__global__ __launch_bounds__(256) void k_edge_max(
    const int* __restrict__ ei,
    const float* __restrict__ a_src, const float* __restrict__ a_dst,
    unsigned int* __restrict__ amax, int E, int N)
{
    int e = blockIdx.x * blockDim.x + threadIdx.x;
    int Et = E + N;
    if (e >= Et) return;
    int s, d;
    if (e < E) { s = ei[e]; d = ei[E + e]; } else { s = d = e - E; }
#pragma unroll
    for (int h = 0; h < HEADS; ++h) {
        float al = a_src[s * HEADS + h] + a_dst[d * HEADS + h];
        al = (al >= 0.f) ? al : NEG_SLOPE * al;
        atomicMax(&amax[d * HEADS + h], fmap(al));
    }
}

// ---------- K3: exp + denom + weighted aggregation (one wave per edge) ----------
__global__ __launch_bounds__(256) void k_edge_agg(
    const int* __restrict__ ei,
    const float* __restrict__ a_src, const float* __restrict__ a_dst,
    const unsigned int* __restrict__ amax,
    const float* __restrict__ xh,
    float* __restrict__ agg, float* __restrict__ denom, int E, int N)
{
    int gtid = blockIdx.x * blockDim.x + threadIdx.x;
    int e = gtid >> 6;
    int lane = threadIdx.x & 63;
    int Et = E + N;
    if (e >= Et) return;
    int s, d;
    if (e < E) { s = ei[e]; d = ei[E + e]; } else { s = d = e - E; }

    int h0 = lane >> 5;        // heads 0/1 for channels 0..63
    int h1 = h0 + 2;           // heads 2/3 for channels 64..127

    float al0 = a_src[s * HEADS + h0] + a_dst[d * HEADS + h0];
    al0 = (al0 >= 0.f) ? al0 : NEG_SLOPE * al0;
    float p0 = __expf(al0 - funmap(amax[d * HEADS + h0]));

    float al1 = a_src[s * HEADS + h1] + a_dst[d * HEADS + h1];
    al1 = (al1 >= 0.f) ? al1 : NEG_SLOPE * al1;
    float p1 = __expf(al1 - funmap(amax[d * HEADS + h1]));

    if ((lane & 31) == 0) {
        atomicAdd(&denom[d * HEADS + h0], p0);
        atomicAdd(&denom[d * HEADS + h1], p1);
    }
    atomicAdd(&agg[d * DIN + lane],      p0 * xh[s * DIN + lane]);
    atomicAdd(&agg[d * DIN + 64 + lane], p1 * xh[s * DIN + 64 + lane]);
}

// ---------- K4: normalize, bias, residual, LN2, FFN, residual ----------
__global__ __launch_bounds__(128) void k_final(
    const float* __restrict__ agg, const float* __restrict__ denom,
    const float* __restrict__ x,
    const float* __restrict__ gat_b,
    const float* __restrict__ g2, const float* __restrict__ b2g,
    const float* __restrict__ w1, const float* __restrict__ bb1,
    const float* __restrict__ w2, const float* __restrict__ bb2,
    float* __restrict__ out, int N)
{
    int n = blockIdx.x, t = threadIdx.x;
    __shared__ float sh[DIN];
    __shared__ float hid[2 * DIN];
    __shared__ float tmp2[2];

    float o = agg[n * DIN + t] / denom[n * HEADS + (t >> 5)] + gat_b[t];
    float hres = o + x[n * DIN + t];

    float mean = block_sum_128(hres, tmp2) * (1.0f / DIN);
    float d = hres - mean;
    float var = block_sum_128(d * d, tmp2) * (1.0f / DIN);
    float hn = d * rsqrtf(var + LN_EPS) * g2[t] + b2g[t];
    sh[t] = hn;
    __syncthreads();

    // hidden layer: each thread does columns t and t+128 of the 256
#pragma unroll
    for (int jj = 0; jj < 2; ++jj) {
        int j = t + jj * DIN;
        float acc = bb1[j];
#pragma unroll 8
        for (int k = 0; k < DIN; ++k)
            acc += sh[k] * w1[k * (2 * DIN) + j];
        // exact GELU
        hid[j] = 0.5f * acc * (1.0f + erff(acc * 0.70710678118654752f));
    }
    __syncthreads();

    float acc2 = bb2[t];
#pragma unroll 8
    for (int j = 0; j < 2 * DIN; ++j)
        acc2 += hid[j] * w2[j * DIN + t];

    out[n * DIN + t] = hres + acc2;
}

extern "C" void kernel_launch(void* const* d_in, const int* in_sizes, int n_in,
                              void* d_out, int out_size, void* d_ws, size_t ws_size,
                              hipStream_t stream) {
    const float* x       = (const float*)d_in[0];
    const int*   ei      = (const int*)d_in[1];
    const float* ln1_g   = (const float*)d_in[2];
    const float* ln1_b   = (const float*)d_in[3];
    const float* W       = (const float*)d_in[4];
    const float* att_src = (const float*)d_in[5];
    const float* att_dst = (const float*)d_in[6];
    const float* gat_b   = (const float*)d_in[7];
    const float* ln2_g   = (const float*)d_in[8];
    const float* ln2_b   = (const float*)d_in[9];
    const float* w1      = (const float*)d_in[10];
    const float* b1      = (const float*)d_in[11];
    const float* w2      = (const float*)d_in[12];
    const float* b2      = (const float*)d_in[13];
    float* out = (float*)d_out;

    const int N = in_sizes[0] / DIN;
    const int E = in_sizes[1] / 2;
    const int Et = E + N;

    // workspace layout (fp32 elements):
    //   [agg N*128][denom N*4][amax N*4 (u32)] <- zeroed
    //   [xh N*128][a_src N*4][a_dst N*4]
    float* ws = (float*)d_ws;
    float*        agg   = ws;
    float*        denom = agg + (size_t)N * DIN;
    unsigned int* amax  = (unsigned int*)(denom + (size_t)N * HEADS);
    float*        xh    = (float*)(amax + (size_t)N * HEADS);
    float*        a_src = xh + (size_t)N * DIN;
    float*        a_dst = a_src + (size_t)N * HEADS;

    size_t zero_bytes = ((size_t)N * (DIN + 2 * HEADS)) * sizeof(float);
    hipMemsetAsync(d_ws, 0, zero_bytes, stream);

    k_ln_proj<<<N, 128, 0, stream>>>(x, ln1_g, ln1_b, W, att_src, att_dst, xh, a_src, a_dst, N);

    int blocks2 = (Et + 255) / 256;
    k_edge_max<<<blocks2, 256, 0, stream>>>(ei, a_src, a_dst, amax, E, N);

    int waves_per_block = 4;
    int blocks3 = (Et + waves_per_block - 1) / waves_per_block;
    k_edge_agg<<<blocks3, 256, 0, stream>>>(ei, a_src, a_dst, amax, xh, agg, denom, E, N);

    k_final<<<N, 128, 0, stream>>>(agg, denom, x, gat_b, ln2_g, ln2_b, w1, b1, w2, b2, out, N);
}

// Round 3
// 881.798 us; speedup vs baseline: 1.3176x; 1.3176x over previous
//
#include <hip/hip_runtime.h>

#define DIN 128
#define HEADS 4
#define CPH 32
#define NEG_SLOPE 0.2f
#define LN_EPS 1e-5f
#define NB 8   // nodes per block in K1/K4

// monotonic float->uint mapping for atomicMax on floats; 0u maps below all finite values
__device__ __forceinline__ unsigned int fmap(float f) {
    unsigned int b = __float_as_uint(f);
    return (b & 0x80000000u) ? ~b : (b | 0x80000000u);
}
__device__ __forceinline__ float funmap(unsigned int m) {
    return (m & 0x80000000u) ? __uint_as_float(m & 0x7FFFFFFFu) : __uint_as_float(~m);
}

__device__ __forceinline__ float wave_allsum(float v) {
#pragma unroll
    for (int off = 32; off > 0; off >>= 1) v += __shfl_down(v, off, 64);
    return __shfl(v, 0, 64);
}

// ---------- K1: LN1 + projection + attention logits (8 nodes / 256 thr) ----------
__global__ __launch_bounds__(256) void k_ln_proj(
    const float* __restrict__ x,
    const float* __restrict__ g1, const float* __restrict__ b1,
    const float* __restrict__ W,
    const float* __restrict__ att_src, const float* __restrict__ att_dst,
    float* __restrict__ xh, float* __restrict__ a_src, float* __restrict__ a_dst, int N)
{
    __shared__ float sh[NB][DIN];   // normalized activations
    __shared__ float sxh[NB][DIN];  // projected
    int t = threadIdx.x;
    int wave = t >> 6, lane = t & 63;
    int nbase = blockIdx.x * NB;

    // Phase A: LN, wave w handles nodes 2w, 2w+1
#pragma unroll
    for (int i = 0; i < 2; ++i) {
        int nn = wave * 2 + i;
        int n = nbase + nn;
        float x0 = 0.f, x1 = 0.f;
        if (n < N) { x0 = x[n * DIN + lane]; x1 = x[n * DIN + 64 + lane]; }
        float mean = wave_allsum(x0 + x1) * (1.0f / DIN);
        float d0 = x0 - mean, d1 = x1 - mean;
        float var = wave_allsum(d0 * d0 + d1 * d1) * (1.0f / DIN);
        float rstd = rsqrtf(var + LN_EPS);
        sh[nn][lane]      = d0 * rstd * g1[lane]      + b1[lane];
        sh[nn][64 + lane] = d1 * rstd * g1[64 + lane] + b1[64 + lane];
    }
    __syncthreads();

    // Phase B: projection; thread t: column j, nodes half*4..half*4+3
    int j = t & (DIN - 1), half = t >> 7;
    int nb0 = half * 4;
    float acc0 = 0.f, acc1 = 0.f, acc2 = 0.f, acc3 = 0.f;
#pragma unroll 4
    for (int k = 0; k < DIN; ++k) {
        float w = W[k * DIN + j];
        acc0 += sh[nb0 + 0][k] * w;
        acc1 += sh[nb0 + 1][k] * w;
        acc2 += sh[nb0 + 2][k] * w;
        acc3 += sh[nb0 + 3][k] * w;
    }
    sxh[nb0 + 0][j] = acc0;
    sxh[nb0 + 1][j] = acc1;
    sxh[nb0 + 2][j] = acc2;
    sxh[nb0 + 3][j] = acc3;
    {
        int n0 = nbase + nb0;
        if (n0 + 0 < N) xh[(n0 + 0) * DIN + j] = acc0;
        if (n0 + 1 < N) xh[(n0 + 1) * DIN + j] = acc1;
        if (n0 + 2 < N) xh[(n0 + 2) * DIN + j] = acc2;
        if (n0 + 3 < N) xh[(n0 + 3) * DIN + j] = acc3;
    }
    __syncthreads();

    // Phase C: attention logits. t = nn(3b) | h(2b) | sub(3b)
    {
        int nn = t >> 5, h = (t >> 3) & 3, sub = t & 7;
        float s1 = 0.f, s2 = 0.f;
#pragma unroll
        for (int i = 0; i < 4; ++i) {
            int c = h * CPH + sub * 4 + i;
            float v = sxh[nn][c];
            s1 += v * att_src[c];
            s2 += v * att_dst[c];
        }
        s1 += __shfl_down(s1, 4, 64); s2 += __shfl_down(s2, 4, 64);
        s1 += __shfl_down(s1, 2, 64); s2 += __shfl_down(s2, 2, 64);
        s1 += __shfl_down(s1, 1, 64); s2 += __shfl_down(s2, 1, 64);
        int n = nbase + nn;
        if (sub == 0 && n < N) {
            a_src[n * HEADS + h] = s1;
            a_dst[n * HEADS + h] = s2;
        }
    }
}

// ---------- K2: segment max over dst ----------
__global__ __launch_bounds__(256) void k_edge_max(
    const int* __restrict__ ei,
    const float* __restrict__ a_src, const float* __restrict__ a_dst,
    unsigned int* __restrict__ amax, int E, int N)
{
    int e = blockIdx.x * blockDim.x + threadIdx.x;
    int Et = E + N;
    if (e >= Et) return;
    int s, d;
    if (e < E) { s = ei[e]; d = ei[E + e]; } else { s = d = e - E; }
#pragma unroll
    for (int h = 0; h < HEADS; ++h) {
        float al = a_src[s * HEADS + h] + a_dst[d * HEADS + h];
        al = (al >= 0.f) ? al : NEG_SLOPE * al;
        atomicMax(&amax[d * HEADS + h], fmap(al));
    }
}

// ---------- K3: exp + denom + weighted aggregation (one wave per edge) ----------
__global__ __launch_bounds__(256) void k_edge_agg(
    const int* __restrict__ ei,
    const float* __restrict__ a_src, const float* __restrict__ a_dst,
    const unsigned int* __restrict__ amax,
    const float* __restrict__ xh,
    float* __restrict__ agg, float* __restrict__ denom, int E, int N)
{
    int gtid = blockIdx.x * blockDim.x + threadIdx.x;
    int e = gtid >> 6;
    int lane = threadIdx.x & 63;
    int Et = E + N;
    if (e >= Et) return;
    int s, d;
    if (e < E) { s = ei[e]; d = ei[E + e]; } else { s = d = e - E; }

    int h0 = lane >> 5;        // heads 0/1 for channels 0..63
    int h1 = h0 + 2;           // heads 2/3 for channels 64..127

    float al0 = a_src[s * HEADS + h0] + a_dst[d * HEADS + h0];
    al0 = (al0 >= 0.f) ? al0 : NEG_SLOPE * al0;
    float p0 = __expf(al0 - funmap(amax[d * HEADS + h0]));

    float al1 = a_src[s * HEADS + h1] + a_dst[d * HEADS + h1];
    al1 = (al1 >= 0.f) ? al1 : NEG_SLOPE * al1;
    float p1 = __expf(al1 - funmap(amax[d * HEADS + h1]));

    if ((lane & 31) == 0) {
        atomicAdd(&denom[d * HEADS + h0], p0);
        atomicAdd(&denom[d * HEADS + h1], p1);
    }
    atomicAdd(&agg[d * DIN + lane],      p0 * xh[s * DIN + lane]);
    atomicAdd(&agg[d * DIN + 64 + lane], p1 * xh[s * DIN + 64 + lane]);
}

// ---------- K4: normalize+bias+residual+LN2+FFN+residual (8 nodes / 256 thr) ----------
__global__ __launch_bounds__(256) void k_final(
    const float* __restrict__ agg, const float* __restrict__ denom,
    const float* __restrict__ x,
    const float* __restrict__ gat_b,
    const float* __restrict__ g2, const float* __restrict__ b2g,
    const float* __restrict__ w1, const float* __restrict__ bb1,
    const float* __restrict__ w2, const float* __restrict__ bb2,
    float* __restrict__ out, int N)
{
    __shared__ float shres[NB][DIN];
    __shared__ float sh[NB][DIN];
    __shared__ float hid[NB][2 * DIN];
    int t = threadIdx.x;
    int wave = t >> 6, lane = t & 63;
    int nbase = blockIdx.x * NB;

    // Phase A: o = agg/denom + bias; residual; LN2. Wave w: nodes 2w, 2w+1.
#pragma unroll
    for (int i = 0; i < 2; ++i) {
        int nn = wave * 2 + i;
        int n = nbase + nn;
        float h0 = 0.f, h1 = 0.f;
        if (n < N) {
            float o0 = agg[n * DIN + lane]      / denom[n * HEADS + (lane >> 5)]     + gat_b[lane];
            float o1 = agg[n * DIN + 64 + lane] / denom[n * HEADS + 2 + (lane >> 5)] + gat_b[64 + lane];
            h0 = o0 + x[n * DIN + lane];
            h1 = o1 + x[n * DIN + 64 + lane];
        }
        float mean = wave_allsum(h0 + h1) * (1.0f / DIN);
        float d0 = h0 - mean, d1 = h1 - mean;
        float var = wave_allsum(d0 * d0 + d1 * d1) * (1.0f / DIN);
        float rstd = rsqrtf(var + LN_EPS);
        shres[nn][lane]      = h0;
        shres[nn][64 + lane] = h1;
        sh[nn][lane]      = d0 * rstd * g2[lane]      + b2g[lane];
        sh[nn][64 + lane] = d1 * rstd * g2[64 + lane] + b2g[64 + lane];
    }
    __syncthreads();

    // Phase B: hidden layer. Thread t owns hidden column t for all 8 nodes.
    {
        float acc[NB];
        float bias = bb1[t];
#pragma unroll
        for (int nn = 0; nn < NB; ++nn) acc[nn] = bias;
#pragma unroll 4
        for (int k = 0; k < DIN; ++k) {
            float w = w1[k * (2 * DIN) + t];
#pragma unroll
            for (int nn = 0; nn < NB; ++nn) acc[nn] += sh[nn][k] * w;
        }
#pragma unroll
        for (int nn = 0; nn < NB; ++nn) {
            float a = acc[nn];
            hid[nn][t] = 0.5f * a * (1.0f + erff(a * 0.70710678118654752f));
        }
    }
    __syncthreads();

    // Phase C: output layer. Thread t: column j, nodes half*4..+3.
    {
        int j = t & (DIN - 1), half = t >> 7;
        int nb0 = half * 4;
        float bias = bb2[j];
        float a0 = bias, a1 = bias, a2 = bias, a3 = bias;
#pragma unroll 4
        for (int jj = 0; jj < 2 * DIN; ++jj) {
            float w = w2[jj * DIN + j];
            a0 += hid[nb0 + 0][jj] * w;
            a1 += hid[nb0 + 1][jj] * w;
            a2 += hid[nb0 + 2][jj] * w;
            a3 += hid[nb0 + 3][jj] * w;
        }
        int n0 = nbase + nb0;
        if (n0 + 0 < N) out[(n0 + 0) * DIN + j] = shres[nb0 + 0][j] + a0;
        if (n0 + 1 < N) out[(n0 + 1) * DIN + j] = shres[nb0 + 1][j] + a1;
        if (n0 + 2 < N) out[(n0 + 2) * DIN + j] = shres[nb0 + 2][j] + a2;
        if (n0 + 3 < N) out[(n0 + 3) * DIN + j] = shres[nb0 + 3][j] + a3;
    }
}

extern "C" void kernel_launch(void* const* d_in, const int* in_sizes, int n_in,
                              void* d_out, int out_size, void* d_ws, size_t ws_size,
                              hipStream_t stream) {
    const float* x       = (const float*)d_in[0];
    const int*   ei      = (const int*)d_in[1];
    const float* ln1_g   = (const float*)d_in[2];
    const float* ln1_b   = (const float*)d_in[3];
    const float* W       = (const float*)d_in[4];
    const float* att_src = (const float*)d_in[5];
    const float* att_dst = (const float*)d_in[6];
    const float* gat_b   = (const float*)d_in[7];
    const float* ln2_g   = (const float*)d_in[8];
    const float* ln2_b   = (const float*)d_in[9];
    const float* w1      = (const float*)d_in[10];
    const float* b1      = (const float*)d_in[11];
    const float* w2      = (const float*)d_in[12];
    const float* b2      = (const float*)d_in[13];
    float* out = (float*)d_out;

    const int N = in_sizes[0] / DIN;
    const int E = in_sizes[1] / 2;
    const int Et = E + N;

    // workspace layout (fp32 elements):
    //   [agg N*128][denom N*4][amax N*4 (u32)] <- zeroed
    //   [xh N*128][a_src N*4][a_dst N*4]
    float* ws = (float*)d_ws;
    float*        agg   = ws;
    float*        denom = agg + (size_t)N * DIN;
    unsigned int* amax  = (unsigned int*)(denom + (size_t)N * HEADS);
    float*        xh    = (float*)(amax + (size_t)N * HEADS);
    float*        a_src = xh + (size_t)N * DIN;
    float*        a_dst = a_src + (size_t)N * HEADS;

    size_t zero_bytes = ((size_t)N * (DIN + 2 * HEADS)) * sizeof(float);
    hipMemsetAsync(d_ws, 0, zero_bytes, stream);

    int nblocks = (N + NB - 1) / NB;
    k_ln_proj<<<nblocks, 256, 0, stream>>>(x, ln1_g, ln1_b, W, att_src, att_dst, xh, a_src, a_dst, N);

    int blocks2 = (Et + 255) / 256;
    k_edge_max<<<blocks2, 256, 0, stream>>>(ei, a_src, a_dst, amax, E, N);

    int waves_per_block = 4;
    int blocks3 = (Et + waves_per_block - 1) / waves_per_block;
    k_edge_agg<<<blocks3, 256, 0, stream>>>(ei, a_src, a_dst, amax, xh, agg, denom, E, N);

    k_final<<<nblocks, 256, 0, stream>>>(agg, denom, x, gat_b, ln2_g, ln2_b, w1, b1, w2, b2, out, N);
}

// Round 4
// 565.813 us; speedup vs baseline: 2.0535x; 1.5585x over previous
//
#include <hip/hip_runtime.h>

#define DIN 128
#define HEADS 4
#define CPH 32
#define NEG_SLOPE 0.2f
#define LN_EPS 1e-5f
#define NB 8   // nodes per block in K1/K4

__device__ __forceinline__ float wave_allsum(float v) {
#pragma unroll
    for (int off = 32; off > 0; off >>= 1) v += __shfl_down(v, off, 64);
    return __shfl(v, 0, 64);
}

// ---------- K1: LN1 + projection + attention logits (8 nodes / 256 thr) ----------
__global__ __launch_bounds__(256) void k_ln_proj(
    const float* __restrict__ x,
    const float* __restrict__ g1, const float* __restrict__ b1,
    const float* __restrict__ W,
    const float* __restrict__ att_src, const float* __restrict__ att_dst,
    float* __restrict__ xh, float* __restrict__ a_src, float* __restrict__ a_dst, int N)
{
    __shared__ float sh[NB][DIN];   // normalized activations
    __shared__ float sxh[NB][DIN];  // projected
    int t = threadIdx.x;
    int wave = t >> 6, lane = t & 63;
    int nbase = blockIdx.x * NB;

#pragma unroll
    for (int i = 0; i < 2; ++i) {
        int nn = wave * 2 + i;
        int n = nbase + nn;
        float x0 = 0.f, x1 = 0.f;
        if (n < N) { x0 = x[n * DIN + lane]; x1 = x[n * DIN + 64 + lane]; }
        float mean = wave_allsum(x0 + x1) * (1.0f / DIN);
        float d0 = x0 - mean, d1 = x1 - mean;
        float var = wave_allsum(d0 * d0 + d1 * d1) * (1.0f / DIN);
        float rstd = rsqrtf(var + LN_EPS);
        sh[nn][lane]      = d0 * rstd * g1[lane]      + b1[lane];
        sh[nn][64 + lane] = d1 * rstd * g1[64 + lane] + b1[64 + lane];
    }
    __syncthreads();

    // projection; thread t: column j, nodes half*4..half*4+3
    int j = t & (DIN - 1), half = t >> 7;
    int nb0 = half * 4;
    float acc0 = 0.f, acc1 = 0.f, acc2 = 0.f, acc3 = 0.f;
#pragma unroll 4
    for (int k = 0; k < DIN; ++k) {
        float w = W[k * DIN + j];
        acc0 += sh[nb0 + 0][k] * w;
        acc1 += sh[nb0 + 1][k] * w;
        acc2 += sh[nb0 + 2][k] * w;
        acc3 += sh[nb0 + 3][k] * w;
    }
    sxh[nb0 + 0][j] = acc0;
    sxh[nb0 + 1][j] = acc1;
    sxh[nb0 + 2][j] = acc2;
    sxh[nb0 + 3][j] = acc3;
    {
        int n0 = nbase + nb0;
        if (n0 + 0 < N) xh[(n0 + 0) * DIN + j] = acc0;
        if (n0 + 1 < N) xh[(n0 + 1) * DIN + j] = acc1;
        if (n0 + 2 < N) xh[(n0 + 2) * DIN + j] = acc2;
        if (n0 + 3 < N) xh[(n0 + 3) * DIN + j] = acc3;
    }
    __syncthreads();

    // attention logits. t = nn(3b) | h(2b) | sub(3b)
    {
        int nn = t >> 5, h = (t >> 3) & 3, sub = t & 7;
        float s1 = 0.f, s2 = 0.f;
#pragma unroll
        for (int i = 0; i < 4; ++i) {
            int c = h * CPH + sub * 4 + i;
            float v = sxh[nn][c];
            s1 += v * att_src[c];
            s2 += v * att_dst[c];
        }
        s1 += __shfl_down(s1, 4, 64); s2 += __shfl_down(s2, 4, 64);
        s1 += __shfl_down(s1, 2, 64); s2 += __shfl_down(s2, 2, 64);
        s1 += __shfl_down(s1, 1, 64); s2 += __shfl_down(s2, 1, 64);
        int n = nbase + nn;
        if (sub == 0 && n < N) {
            a_src[n * HEADS + h] = s1;
            a_dst[n * HEADS + h] = s2;
        }
    }
}

// ---------- CSR build: histogram ----------
__global__ __launch_bounds__(256) void k_hist(
    const int* __restrict__ ei, unsigned int* __restrict__ cnt, int E, int N)
{
    int e = blockIdx.x * blockDim.x + threadIdx.x;
    int Et = E + N;
    if (e >= Et) return;
    int d = (e < E) ? ei[E + e] : (e - E);
    atomicAdd(&cnt[d], 1u);
}

// ---------- CSR build: per-block partial sums ----------
__global__ __launch_bounds__(256) void k_partsum(
    const unsigned int* __restrict__ cnt, unsigned int* __restrict__ bsum, int N)
{
    __shared__ unsigned int sm[4];
    int t = threadIdx.x;
    int i = blockIdx.x * 256 + t;
    unsigned int v = (i < N) ? cnt[i] : 0u;
#pragma unroll
    for (int off = 32; off > 0; off >>= 1) v += (unsigned int)__shfl_down((int)v, off, 64);
    if ((t & 63) == 0) sm[t >> 6] = v;
    __syncthreads();
    if (t == 0) bsum[blockIdx.x] = sm[0] + sm[1] + sm[2] + sm[3];
}

// ---------- CSR build: scan of block sums (single block, up to 256 blocks) ----------
__global__ __launch_bounds__(256) void k_scanb(
    const unsigned int* __restrict__ bsum, unsigned int* __restrict__ boff,
    unsigned int* __restrict__ row, int nb2, int N, int Et)
{
    __shared__ unsigned int sm[256];
    int t = threadIdx.x;
    unsigned int v = (t < nb2) ? bsum[t] : 0u;
    sm[t] = v;
    __syncthreads();
#pragma unroll
    for (int off = 1; off < 256; off <<= 1) {
        unsigned int a = (t >= off) ? sm[t - off] : 0u;
        __syncthreads();
        sm[t] += a;
        __syncthreads();
    }
    if (t < nb2) boff[t] = sm[t] - v;
    if (t == 0) row[N] = (unsigned int)Et;
}

// ---------- CSR build: per-element exclusive scan ----------
__global__ __launch_bounds__(256) void k_scanw(
    const unsigned int* __restrict__ cnt, const unsigned int* __restrict__ boff,
    unsigned int* __restrict__ row, unsigned int* __restrict__ pos, int N)
{
    __shared__ unsigned int sm[256];
    int t = threadIdx.x;
    int i = blockIdx.x * 256 + t;
    unsigned int v = (i < N) ? cnt[i] : 0u;
    sm[t] = v;
    __syncthreads();
#pragma unroll
    for (int off = 1; off < 256; off <<= 1) {
        unsigned int a = (t >= off) ? sm[t - off] : 0u;
        __syncthreads();
        sm[t] += a;
        __syncthreads();
    }
    if (i < N) {
        unsigned int o = boff[blockIdx.x] + sm[t] - v;
        row[i] = o;
        pos[i] = o;
    }
}

// ---------- CSR build: scatter src indices ----------
__global__ __launch_bounds__(256) void k_scatter(
    const int* __restrict__ ei, unsigned int* __restrict__ pos,
    int* __restrict__ srcs, int E, int N)
{
    int e = blockIdx.x * blockDim.x + threadIdx.x;
    int Et = E + N;
    if (e >= Et) return;
    int s, d;
    if (e < E) { s = ei[e]; d = ei[E + e]; } else { s = d = e - E; }
    unsigned int p = atomicAdd(&pos[d], 1u);
    srcs[p] = s;
}

// ---------- K3: segment softmax + aggregation, one wave per dst ----------
__global__ __launch_bounds__(256) void k_agg(
    const unsigned int* __restrict__ row, const int* __restrict__ srcs,
    const float* __restrict__ a_src, const float* __restrict__ a_dst,
    const float* __restrict__ xh, float* __restrict__ aggN, int N)
{
    int w = threadIdx.x >> 6, lane = threadIdx.x & 63;
    int d = blockIdx.x * 4 + w;
    if (d >= N) return;
    int h0 = lane >> 5, h1 = h0 + 2;
    float ad0 = a_dst[d * HEADS + h0];
    float ad1 = a_dst[d * HEADS + h1];
    int start = (int)row[d], end = (int)row[d + 1];

    float m0 = -3.4e38f, m1 = -3.4e38f;
    for (int e = start; e < end; ++e) {
        int s = srcs[e];
        float al0 = a_src[s * HEADS + h0] + ad0; al0 = (al0 >= 0.f) ? al0 : NEG_SLOPE * al0;
        float al1 = a_src[s * HEADS + h1] + ad1; al1 = (al1 >= 0.f) ? al1 : NEG_SLOPE * al1;
        m0 = fmaxf(m0, al0);
        m1 = fmaxf(m1, al1);
    }

    float den0 = 0.f, den1 = 0.f, acc0 = 0.f, acc1 = 0.f;
    for (int e = start; e < end; ++e) {
        int s = srcs[e];
        float al0 = a_src[s * HEADS + h0] + ad0; al0 = (al0 >= 0.f) ? al0 : NEG_SLOPE * al0;
        float al1 = a_src[s * HEADS + h1] + ad1; al1 = (al1 >= 0.f) ? al1 : NEG_SLOPE * al1;
        float p0 = __expf(al0 - m0);
        float p1 = __expf(al1 - m1);
        den0 += p0; den1 += p1;
        acc0 += p0 * xh[s * DIN + lane];
        acc1 += p1 * xh[s * DIN + 64 + lane];
    }
    aggN[d * DIN + lane]      = acc0 / den0;
    aggN[d * DIN + 64 + lane] = acc1 / den1;
}

// ---------- K4: bias+residual+LN2+FFN+residual (8 nodes / 256 thr) ----------
__global__ __launch_bounds__(256) void k_final(
    const float* __restrict__ aggN,
    const float* __restrict__ x,
    const float* __restrict__ gat_b,
    const float* __restrict__ g2, const float* __restrict__ b2g,
    const float* __restrict__ w1, const float* __restrict__ bb1,
    const float* __restrict__ w2, const float* __restrict__ bb2,
    float* __restrict__ out, int N)
{
    __shared__ float shres[NB][DIN];
    __shared__ float sh[NB][DIN];
    __shared__ float hid[NB][2 * DIN];
    int t = threadIdx.x;
    int wave = t >> 6, lane = t & 63;
    int nbase = blockIdx.x * NB;

#pragma unroll
    for (int i = 0; i < 2; ++i) {
        int nn = wave * 2 + i;
        int n = nbase + nn;
        float h0 = 0.f, h1 = 0.f;
        if (n < N) {
            h0 = aggN[n * DIN + lane]      + gat_b[lane]      + x[n * DIN + lane];
            h1 = aggN[n * DIN + 64 + lane] + gat_b[64 + lane] + x[n * DIN + 64 + lane];
        }
        float mean = wave_allsum(h0 + h1) * (1.0f / DIN);
        float d0 = h0 - mean, d1 = h1 - mean;
        float var = wave_allsum(d0 * d0 + d1 * d1) * (1.0f / DIN);
        float rstd = rsqrtf(var + LN_EPS);
        shres[nn][lane]      = h0;
        shres[nn][64 + lane] = h1;
        sh[nn][lane]      = d0 * rstd * g2[lane]      + b2g[lane];
        sh[nn][64 + lane] = d1 * rstd * g2[64 + lane] + b2g[64 + lane];
    }
    __syncthreads();

    // hidden layer: thread t owns hidden column t for all 8 nodes
    {
        float acc[NB];
        float bias = bb1[t];
#pragma unroll
        for (int nn = 0; nn < NB; ++nn) acc[nn] = bias;
#pragma unroll 4
        for (int k = 0; k < DIN; ++k) {
            float w = w1[k * (2 * DIN) + t];
#pragma unroll
            for (int nn = 0; nn < NB; ++nn) acc[nn] += sh[nn][k] * w;
        }
#pragma unroll
        for (int nn = 0; nn < NB; ++nn) {
            float a = acc[nn];
            hid[nn][t] = 0.5f * a * (1.0f + erff(a * 0.70710678118654752f));
        }
    }
    __syncthreads();

    // output layer: thread t: column j, nodes half*4..+3
    {
        int j = t & (DIN - 1), half = t >> 7;
        int nb0 = half * 4;
        float bias = bb2[j];
        float a0 = bias, a1 = bias, a2 = bias, a3 = bias;
#pragma unroll 4
        for (int jj = 0; jj < 2 * DIN; ++jj) {
            float w = w2[jj * DIN + j];
            a0 += hid[nb0 + 0][jj] * w;
            a1 += hid[nb0 + 1][jj] * w;
            a2 += hid[nb0 + 2][jj] * w;
            a3 += hid[nb0 + 3][jj] * w;
        }
        int n0 = nbase + nb0;
        if (n0 + 0 < N) out[(n0 + 0) * DIN + j] = shres[nb0 + 0][j] + a0;
        if (n0 + 1 < N) out[(n0 + 1) * DIN + j] = shres[nb0 + 1][j] + a1;
        if (n0 + 2 < N) out[(n0 + 2) * DIN + j] = shres[nb0 + 2][j] + a2;
        if (n0 + 3 < N) out[(n0 + 3) * DIN + j] = shres[nb0 + 3][j] + a3;
    }
}

extern "C" void kernel_launch(void* const* d_in, const int* in_sizes, int n_in,
                              void* d_out, int out_size, void* d_ws, size_t ws_size,
                              hipStream_t stream) {
    const float* x       = (const float*)d_in[0];
    const int*   ei      = (const int*)d_in[1];
    const float* ln1_g   = (const float*)d_in[2];
    const float* ln1_b   = (const float*)d_in[3];
    const float* W       = (const float*)d_in[4];
    const float* att_src = (const float*)d_in[5];
    const float* att_dst = (const float*)d_in[6];
    const float* gat_b   = (const float*)d_in[7];
    const float* ln2_g   = (const float*)d_in[8];
    const float* ln2_b   = (const float*)d_in[9];
    const float* w1      = (const float*)d_in[10];
    const float* b1      = (const float*)d_in[11];
    const float* w2      = (const float*)d_in[12];
    const float* b2      = (const float*)d_in[13];
    float* out = (float*)d_out;

    const int N = in_sizes[0] / DIN;
    const int E = in_sizes[1] / 2;
    const int Et = E + N;

    // workspace layout:
    //   u32 cnt[N] (zeroed) | u32 row[N+1] | u32 pos[N] | u32 bsum[256] | u32 boff[256]
    //   int srcs[Et] | f32 xh[N*128] | f32 a_src[N*4] | f32 a_dst[N*4] | f32 aggN[N*128]
    unsigned int* cnt  = (unsigned int*)d_ws;
    unsigned int* row  = cnt + N;
    unsigned int* pos  = row + N + 1;
    unsigned int* bsum = pos + N;
    unsigned int* boff = bsum + 256;
    int*          srcs = (int*)(boff + 256);
    float*        xh   = (float*)(srcs + Et);
    float*        a_src = xh + (size_t)N * DIN;
    float*        a_dst = a_src + (size_t)N * HEADS;
    float*        aggN  = a_dst + (size_t)N * HEADS;

    hipMemsetAsync(cnt, 0, (size_t)N * sizeof(unsigned int), stream);

    int nblocks = (N + NB - 1) / NB;
    k_ln_proj<<<nblocks, 256, 0, stream>>>(x, ln1_g, ln1_b, W, att_src, att_dst, xh, a_src, a_dst, N);

    int eblocks = (Et + 255) / 256;
    int nb2 = (N + 255) / 256;   // must be <= 256 (N <= 65536)
    k_hist<<<eblocks, 256, 0, stream>>>(ei, cnt, E, N);
    k_partsum<<<nb2, 256, 0, stream>>>(cnt, bsum, N);
    k_scanb<<<1, 256, 0, stream>>>(bsum, boff, row, nb2, N, Et);
    k_scanw<<<nb2, 256, 0, stream>>>(cnt, boff, row, pos, N);
    k_scatter<<<eblocks, 256, 0, stream>>>(ei, pos, srcs, E, N);

    int ablocks = (N + 3) / 4;
    k_agg<<<ablocks, 256, 0, stream>>>(row, srcs, a_src, a_dst, xh, aggN, N);

    k_final<<<nblocks, 256, 0, stream>>>(aggN, x, gat_b, ln2_g, ln2_b, w1, b1, w2, b2, out, N);
}

// Round 5
// 487.973 us; speedup vs baseline: 2.3810x; 1.1595x over previous
//
#include <hip/hip_runtime.h>

#define DIN 128
#define HEADS 4
#define CPH 32
#define NEG_SLOPE 0.2f
#define LN_EPS 1e-5f
#define NB 8   // nodes per block in K1/K4

__device__ __forceinline__ float wave_allsum(float v) {
#pragma unroll
    for (int off = 32; off > 0; off >>= 1) v += __shfl_down(v, off, 64);
    return __shfl(v, 0, 64);
}

// round-to-nearest-even fp32 -> bf16 bits
__device__ __forceinline__ unsigned short f2bf(float f) {
    unsigned int b = __float_as_uint(f);
    b += 0x7FFFu + ((b >> 16) & 1u);
    return (unsigned short)(b >> 16);
}

// ---------- K1: LN1 + projection + attention logits (8 nodes / 256 thr) ----------
__global__ __launch_bounds__(256) void k_ln_proj(
    const float* __restrict__ x,
    const float* __restrict__ g1, const float* __restrict__ b1,
    const float* __restrict__ W,
    const float* __restrict__ att_src, const float* __restrict__ att_dst,
    unsigned short* __restrict__ xhb, float* __restrict__ a_src, float* __restrict__ a_dst, int N)
{
    __shared__ float sh[NB][DIN];   // normalized activations
    __shared__ float sxh[NB][DIN];  // projected
    int t = threadIdx.x;
    int wave = t >> 6, lane = t & 63;
    int nbase = blockIdx.x * NB;

#pragma unroll
    for (int i = 0; i < 2; ++i) {
        int nn = wave * 2 + i;
        int n = nbase + nn;
        float x0 = 0.f, x1 = 0.f;
        if (n < N) { x0 = x[n * DIN + lane]; x1 = x[n * DIN + 64 + lane]; }
        float mean = wave_allsum(x0 + x1) * (1.0f / DIN);
        float d0 = x0 - mean, d1 = x1 - mean;
        float var = wave_allsum(d0 * d0 + d1 * d1) * (1.0f / DIN);
        float rstd = rsqrtf(var + LN_EPS);
        sh[nn][lane]      = d0 * rstd * g1[lane]      + b1[lane];
        sh[nn][64 + lane] = d1 * rstd * g1[64 + lane] + b1[64 + lane];
    }
    __syncthreads();

    // projection; thread t: column j, nodes half*4..half*4+3
    int j = t & (DIN - 1), half = t >> 7;
    int nb0 = half * 4;
    float acc0 = 0.f, acc1 = 0.f, acc2 = 0.f, acc3 = 0.f;
#pragma unroll 4
    for (int k = 0; k < DIN; ++k) {
        float w = W[k * DIN + j];
        acc0 += sh[nb0 + 0][k] * w;
        acc1 += sh[nb0 + 1][k] * w;
        acc2 += sh[nb0 + 2][k] * w;
        acc3 += sh[nb0 + 3][k] * w;
    }
    sxh[nb0 + 0][j] = acc0;
    sxh[nb0 + 1][j] = acc1;
    sxh[nb0 + 2][j] = acc2;
    sxh[nb0 + 3][j] = acc3;
    {
        int n0 = nbase + nb0;
        if (n0 + 0 < N) xhb[(size_t)(n0 + 0) * DIN + j] = f2bf(acc0);
        if (n0 + 1 < N) xhb[(size_t)(n0 + 1) * DIN + j] = f2bf(acc1);
        if (n0 + 2 < N) xhb[(size_t)(n0 + 2) * DIN + j] = f2bf(acc2);
        if (n0 + 3 < N) xhb[(size_t)(n0 + 3) * DIN + j] = f2bf(acc3);
    }
    __syncthreads();

    // attention logits. t = nn(3b) | h(2b) | sub(3b)
    {
        int nn = t >> 5, h = (t >> 3) & 3, sub = t & 7;
        float s1 = 0.f, s2 = 0.f;
#pragma unroll
        for (int i = 0; i < 4; ++i) {
            int c = h * CPH + sub * 4 + i;
            float v = sxh[nn][c];
            s1 += v * att_src[c];
            s2 += v * att_dst[c];
        }
        s1 += __shfl_down(s1, 4, 64); s2 += __shfl_down(s2, 4, 64);
        s1 += __shfl_down(s1, 2, 64); s2 += __shfl_down(s2, 2, 64);
        s1 += __shfl_down(s1, 1, 64); s2 += __shfl_down(s2, 1, 64);
        int n = nbase + nn;
        if (sub == 0 && n < N) {
            a_src[n * HEADS + h] = s1;
            a_dst[n * HEADS + h] = s2;
        }
    }
}

// ---------- CSR build: histogram ----------
__global__ __launch_bounds__(256) void k_hist(
    const int* __restrict__ ei, unsigned int* __restrict__ cnt, int E, int N)
{
    int e = blockIdx.x * blockDim.x + threadIdx.x;
    int Et = E + N;
    if (e >= Et) return;
    int d = (e < E) ? ei[E + e] : (e - E);
    atomicAdd(&cnt[d], 1u);
}

// ---------- CSR build: per-block partial sums ----------
__global__ __launch_bounds__(256) void k_partsum(
    const unsigned int* __restrict__ cnt, unsigned int* __restrict__ bsum, int N)
{
    __shared__ unsigned int sm[4];
    int t = threadIdx.x;
    int i = blockIdx.x * 256 + t;
    unsigned int v = (i < N) ? cnt[i] : 0u;
#pragma unroll
    for (int off = 32; off > 0; off >>= 1) v += (unsigned int)__shfl_down((int)v, off, 64);
    if ((t & 63) == 0) sm[t >> 6] = v;
    __syncthreads();
    if (t == 0) bsum[blockIdx.x] = sm[0] + sm[1] + sm[2] + sm[3];
}

// ---------- CSR build: scan of block sums (single block, up to 256 blocks) ----------
__global__ __launch_bounds__(256) void k_scanb(
    const unsigned int* __restrict__ bsum, unsigned int* __restrict__ boff,
    unsigned int* __restrict__ row, int nb2, int N, int Et)
{
    __shared__ unsigned int sm[256];
    int t = threadIdx.x;
    unsigned int v = (t < nb2) ? bsum[t] : 0u;
    sm[t] = v;
    __syncthreads();
#pragma unroll
    for (int off = 1; off < 256; off <<= 1) {
        unsigned int a = (t >= off) ? sm[t - off] : 0u;
        __syncthreads();
        sm[t] += a;
        __syncthreads();
    }
    if (t < nb2) boff[t] = sm[t] - v;
    if (t == 0) row[N] = (unsigned int)Et;
}

// ---------- CSR build: per-element exclusive scan ----------
__global__ __launch_bounds__(256) void k_scanw(
    const unsigned int* __restrict__ cnt, const unsigned int* __restrict__ boff,
    unsigned int* __restrict__ row, unsigned int* __restrict__ pos, int N)
{
    __shared__ unsigned int sm[256];
    int t = threadIdx.x;
    int i = blockIdx.x * 256 + t;
    unsigned int v = (i < N) ? cnt[i] : 0u;
    sm[t] = v;
    __syncthreads();
#pragma unroll
    for (int off = 1; off < 256; off <<= 1) {
        unsigned int a = (t >= off) ? sm[t - off] : 0u;
        __syncthreads();
        sm[t] += a;
        __syncthreads();
    }
    if (i < N) {
        unsigned int o = boff[blockIdx.x] + sm[t] - v;
        row[i] = o;
        pos[i] = o;
    }
}

// ---------- CSR build: scatter src indices ----------
__global__ __launch_bounds__(256) void k_scatter(
    const int* __restrict__ ei, unsigned int* __restrict__ pos,
    int* __restrict__ srcs, int E, int N)
{
    int e = blockIdx.x * blockDim.x + threadIdx.x;
    int Et = E + N;
    if (e >= Et) return;
    int s, d;
    if (e < E) { s = ei[e]; d = ei[E + e]; } else { s = d = e - E; }
    unsigned int p = atomicAdd(&pos[d], 1u);
    srcs[p] = s;
}

// ---------- K3: segment softmax + aggregation, one wave per dst ----------
__global__ __launch_bounds__(256) void k_agg(
    const unsigned int* __restrict__ row, const int* __restrict__ srcs,
    const float* __restrict__ a_src, const float* __restrict__ a_dst,
    const unsigned int* __restrict__ xhb,   // packed bf16 pairs, N*64 words
    float* __restrict__ aggN, int N)
{
    int w = threadIdx.x >> 6, lane = threadIdx.x & 63;
    int d = blockIdx.x * 4 + w;
    if (d >= N) return;
    int start = (int)row[d], end = (int)row[d + 1];

    // ---- pass 1: per-head max; edges distributed across 16 lane-groups ----
    int hm = lane & 3;
    float adm = a_dst[d * HEADS + hm];
    float m = -3.4e38f;
    for (int e = start + (lane >> 2); e < end; e += 16) {
        int s = srcs[e];
        float al = a_src[s * HEADS + hm] + adm;
        al = (al >= 0.f) ? al : NEG_SLOPE * al;
        m = fmaxf(m, al);
    }
#pragma unroll
    for (int off = 4; off < 64; off <<= 1)
        m = fmaxf(m, __shfl_xor(m, off, 64));
    // lane l now holds the max for head l&3

    // ---- pass 2: lane covers channels 2*lane, 2*lane+1; head = lane>>4 ----
    int h = lane >> 4;
    float mh  = __shfl(m, h, 64);
    float adh = __shfl(adm, h, 64);   // lane h holds a_dst for head h

    float den = 0.f, acc0 = 0.f, acc1 = 0.f;
    int s_cur = srcs[start];
    for (int e = start; e < end; ++e) {
        int s_next = (e + 1 < end) ? srcs[e + 1] : 0;
        float as = a_src[s_cur * HEADS + h];
        unsigned int u = xhb[(size_t)s_cur * 64 + lane];
        float al = as + adh;
        al = (al >= 0.f) ? al : NEG_SLOPE * al;
        float p = __expf(al - mh);
        den += p;
        acc0 += p * __uint_as_float(u << 16);
        acc1 += p * __uint_as_float(u & 0xFFFF0000u);
        s_cur = s_next;
    }
    float inv = 1.0f / den;
    float2 o; o.x = acc0 * inv; o.y = acc1 * inv;
    ((float2*)aggN)[(size_t)d * 64 + lane] = o;
}

// ---------- K4: bias+residual+LN2+FFN+residual (8 nodes / 256 thr) ----------
__global__ __launch_bounds__(256) void k_final(
    const float* __restrict__ aggN,
    const float* __restrict__ x,
    const float* __restrict__ gat_b,
    const float* __restrict__ g2, const float* __restrict__ b2g,
    const float* __restrict__ w1, const float* __restrict__ bb1,
    const float* __restrict__ w2, const float* __restrict__ bb2,
    float* __restrict__ out, int N)
{
    __shared__ float shres[NB][DIN];
    __shared__ float sh[NB][DIN];
    __shared__ float hid[NB][2 * DIN];
    int t = threadIdx.x;
    int wave = t >> 6, lane = t & 63;
    int nbase = blockIdx.x * NB;

#pragma unroll
    for (int i = 0; i < 2; ++i) {
        int nn = wave * 2 + i;
        int n = nbase + nn;
        float h0 = 0.f, h1 = 0.f;
        if (n < N) {
            h0 = aggN[n * DIN + lane]      + gat_b[lane]      + x[n * DIN + lane];
            h1 = aggN[n * DIN + 64 + lane] + gat_b[64 + lane] + x[n * DIN + 64 + lane];
        }
        float mean = wave_allsum(h0 + h1) * (1.0f / DIN);
        float d0 = h0 - mean, d1 = h1 - mean;
        float var = wave_allsum(d0 * d0 + d1 * d1) * (1.0f / DIN);
        float rstd = rsqrtf(var + LN_EPS);
        shres[nn][lane]      = h0;
        shres[nn][64 + lane] = h1;
        sh[nn][lane]      = d0 * rstd * g2[lane]      + b2g[lane];
        sh[nn][64 + lane] = d1 * rstd * g2[64 + lane] + b2g[64 + lane];
    }
    __syncthreads();

    // hidden layer: thread t owns hidden column t for all 8 nodes
    {
        float acc[NB];
        float bias = bb1[t];
#pragma unroll
        for (int nn = 0; nn < NB; ++nn) acc[nn] = bias;
#pragma unroll 4
        for (int k = 0; k < DIN; ++k) {
            float w = w1[k * (2 * DIN) + t];
#pragma unroll
            for (int nn = 0; nn < NB; ++nn) acc[nn] += sh[nn][k] * w;
        }
#pragma unroll
        for (int nn = 0; nn < NB; ++nn) {
            float a = acc[nn];
            hid[nn][t] = 0.5f * a * (1.0f + erff(a * 0.70710678118654752f));
        }
    }
    __syncthreads();

    // output layer: thread t: column j, nodes half*4..+3
    {
        int j = t & (DIN - 1), half = t >> 7;
        int nb0 = half * 4;
        float bias = bb2[j];
        float a0 = bias, a1 = bias, a2 = bias, a3 = bias;
#pragma unroll 4
        for (int jj = 0; jj < 2 * DIN; ++jj) {
            float w = w2[jj * DIN + j];
            a0 += hid[nb0 + 0][jj] * w;
            a1 += hid[nb0 + 1][jj] * w;
            a2 += hid[nb0 + 2][jj] * w;
            a3 += hid[nb0 + 3][jj] * w;
        }
        int n0 = nbase + nb0;
        if (n0 + 0 < N) out[(n0 + 0) * DIN + j] = shres[nb0 + 0][j] + a0;
        if (n0 + 1 < N) out[(n0 + 1) * DIN + j] = shres[nb0 + 1][j] + a1;
        if (n0 + 2 < N) out[(n0 + 2) * DIN + j] = shres[nb0 + 2][j] + a2;
        if (n0 + 3 < N) out[(n0 + 3) * DIN + j] = shres[nb0 + 3][j] + a3;
    }
}

extern "C" void kernel_launch(void* const* d_in, const int* in_sizes, int n_in,
                              void* d_out, int out_size, void* d_ws, size_t ws_size,
                              hipStream_t stream) {
    const float* x       = (const float*)d_in[0];
    const int*   ei      = (const int*)d_in[1];
    const float* ln1_g   = (const float*)d_in[2];
    const float* ln1_b   = (const float*)d_in[3];
    const float* W       = (const float*)d_in[4];
    const float* att_src = (const float*)d_in[5];
    const float* att_dst = (const float*)d_in[6];
    const float* gat_b   = (const float*)d_in[7];
    const float* ln2_g   = (const float*)d_in[8];
    const float* ln2_b   = (const float*)d_in[9];
    const float* w1      = (const float*)d_in[10];
    const float* b1      = (const float*)d_in[11];
    const float* w2      = (const float*)d_in[12];
    const float* b2      = (const float*)d_in[13];
    float* out = (float*)d_out;

    const int N = in_sizes[0] / DIN;
    const int E = in_sizes[1] / 2;
    const int Et = E + N;

    // workspace layout:
    //   u32 cnt[N] (zeroed) | u32 row[N+1] | u32 pos[N] | u32 bsum[256] | u32 boff[256]
    //   int srcs[Et] | u16 xhb[N*128] | f32 a_src[N*4] | f32 a_dst[N*4] | f32 aggN[N*128]
    unsigned int* cnt  = (unsigned int*)d_ws;
    unsigned int* row  = cnt + N;
    unsigned int* pos  = row + N + 1;
    unsigned int* bsum = pos + N;
    unsigned int* boff = bsum + 256;
    int*           srcs = (int*)(boff + 256);
    unsigned short* xhb = (unsigned short*)(srcs + Et);
    float*        a_src = (float*)(xhb + (size_t)N * DIN);
    float*        a_dst = a_src + (size_t)N * HEADS;
    float*        aggN  = a_dst + (size_t)N * HEADS;

    hipMemsetAsync(cnt, 0, (size_t)N * sizeof(unsigned int), stream);

    int nblocks = (N + NB - 1) / NB;
    k_ln_proj<<<nblocks, 256, 0, stream>>>(x, ln1_g, ln1_b, W, att_src, att_dst, xhb, a_src, a_dst, N);

    int eblocks = (Et + 255) / 256;
    int nb2 = (N + 255) / 256;   // must be <= 256 (N <= 65536)
    k_hist<<<eblocks, 256, 0, stream>>>(ei, cnt, E, N);
    k_partsum<<<nb2, 256, 0, stream>>>(cnt, bsum, N);
    k_scanb<<<1, 256, 0, stream>>>(bsum, boff, row, nb2, N, Et);
    k_scanw<<<nb2, 256, 0, stream>>>(cnt, boff, row, pos, N);
    k_scatter<<<eblocks, 256, 0, stream>>>(ei, pos, srcs, E, N);

    int ablocks = (N + 3) / 4;
    k_agg<<<ablocks, 256, 0, stream>>>(row, srcs, a_src, a_dst, (const unsigned int*)xhb, aggN, N);

    k_final<<<nblocks, 256, 0, stream>>>(aggN, x, gat_b, ln2_g, ln2_b, w1, b1, w2, b2, out, N);
}

// Round 6
// 394.282 us; speedup vs baseline: 2.9468x; 1.2376x over previous
//
#include <hip/hip_runtime.h>

#define DIN 128
#define HEADS 4
#define CPH 32
#define NEG_SLOPE 0.2f
#define LN_EPS 1e-5f
#define NB 8    // nodes per block in K1
#define NPB 32  // nodes per block in K4 (MFMA)

typedef short bf16x8 __attribute__((ext_vector_type(8)));
typedef float f32x4 __attribute__((ext_vector_type(4)));

__device__ __forceinline__ float wave_allsum(float v) {
#pragma unroll
    for (int off = 32; off > 0; off >>= 1) v += __shfl_down(v, off, 64);
    return __shfl(v, 0, 64);
}

// round-to-nearest-even fp32 -> bf16 bits
__device__ __forceinline__ unsigned short f2bf(float f) {
    unsigned int b = __float_as_uint(f);
    b += 0x7FFFu + ((b >> 16) & 1u);
    return (unsigned short)(b >> 16);
}

// ---------- K1: LN1 + projection + attention logits (8 nodes / 256 thr) ----------
__global__ __launch_bounds__(256) void k_ln_proj(
    const float* __restrict__ x,
    const float* __restrict__ g1, const float* __restrict__ b1,
    const float* __restrict__ W,
    const float* __restrict__ att_src, const float* __restrict__ att_dst,
    unsigned short* __restrict__ xhb, float* __restrict__ a_src, float* __restrict__ a_dst, int N)
{
    __shared__ float sh[NB][DIN];   // normalized activations
    __shared__ float sxh[NB][DIN];  // projected
    int t = threadIdx.x;
    int wave = t >> 6, lane = t & 63;
    int nbase = blockIdx.x * NB;

#pragma unroll
    for (int i = 0; i < 2; ++i) {
        int nn = wave * 2 + i;
        int n = nbase + nn;
        float x0 = 0.f, x1 = 0.f;
        if (n < N) { x0 = x[n * DIN + lane]; x1 = x[n * DIN + 64 + lane]; }
        float mean = wave_allsum(x0 + x1) * (1.0f / DIN);
        float d0 = x0 - mean, d1 = x1 - mean;
        float var = wave_allsum(d0 * d0 + d1 * d1) * (1.0f / DIN);
        float rstd = rsqrtf(var + LN_EPS);
        sh[nn][lane]      = d0 * rstd * g1[lane]      + b1[lane];
        sh[nn][64 + lane] = d1 * rstd * g1[64 + lane] + b1[64 + lane];
    }
    __syncthreads();

    // projection; thread t: column j, nodes half*4..half*4+3
    int j = t & (DIN - 1), half = t >> 7;
    int nb0 = half * 4;
    float acc0 = 0.f, acc1 = 0.f, acc2 = 0.f, acc3 = 0.f;
#pragma unroll 4
    for (int k = 0; k < DIN; ++k) {
        float w = W[k * DIN + j];
        acc0 += sh[nb0 + 0][k] * w;
        acc1 += sh[nb0 + 1][k] * w;
        acc2 += sh[nb0 + 2][k] * w;
        acc3 += sh[nb0 + 3][k] * w;
    }
    sxh[nb0 + 0][j] = acc0;
    sxh[nb0 + 1][j] = acc1;
    sxh[nb0 + 2][j] = acc2;
    sxh[nb0 + 3][j] = acc3;
    {
        int n0 = nbase + nb0;
        if (n0 + 0 < N) xhb[(size_t)(n0 + 0) * DIN + j] = f2bf(acc0);
        if (n0 + 1 < N) xhb[(size_t)(n0 + 1) * DIN + j] = f2bf(acc1);
        if (n0 + 2 < N) xhb[(size_t)(n0 + 2) * DIN + j] = f2bf(acc2);
        if (n0 + 3 < N) xhb[(size_t)(n0 + 3) * DIN + j] = f2bf(acc3);
    }
    __syncthreads();

    // attention logits. t = nn(3b) | h(2b) | sub(3b)
    {
        int nn = t >> 5, h = (t >> 3) & 3, sub = t & 7;
        float s1 = 0.f, s2 = 0.f;
#pragma unroll
        for (int i = 0; i < 4; ++i) {
            int c = h * CPH + sub * 4 + i;
            float v = sxh[nn][c];
            s1 += v * att_src[c];
            s2 += v * att_dst[c];
        }
        s1 += __shfl_down(s1, 4, 64); s2 += __shfl_down(s2, 4, 64);
        s1 += __shfl_down(s1, 2, 64); s2 += __shfl_down(s2, 2, 64);
        s1 += __shfl_down(s1, 1, 64); s2 += __shfl_down(s2, 1, 64);
        int n = nbase + nn;
        if (sub == 0 && n < N) {
            a_src[n * HEADS + h] = s1;
            a_dst[n * HEADS + h] = s2;
        }
    }
}

// ---------- pack w1/w2 into bf16 MFMA B-fragment order ----------
// wp1[((tile*4+ks)*64+lane)*8+j] = w1[(ks*32+(lane>>4)*8+j)*256 + tile*16+(lane&15)]
// wp2[((tile*8+ks)*64+lane)*8+j] = w2[(ks*32+(lane>>4)*8+j)*128 + tile*16+(lane&15)]
__global__ __launch_bounds__(256) void k_pack(
    const float* __restrict__ w1, const float* __restrict__ w2,
    unsigned short* __restrict__ wp1, unsigned short* __restrict__ wp2)
{
    int idx = blockIdx.x * 256 + threadIdx.x;
    if (idx < 32768) {
        int j = idx & 7, lane = (idx >> 3) & 63, tk = idx >> 9;
        int ks = tk & 3, tile = tk >> 2;
        int k = ks * 32 + ((lane >> 4) << 3) + j;
        int n = tile * 16 + (lane & 15);
        wp1[idx] = f2bf(w1[k * 256 + n]);
    } else {
        int i2 = idx - 32768;
        int j = i2 & 7, lane = (i2 >> 3) & 63, tk = i2 >> 9;
        int ks = tk & 7, tile = tk >> 3;
        int k = ks * 32 + ((lane >> 4) << 3) + j;
        int n = tile * 16 + (lane & 15);
        wp2[i2] = f2bf(w2[k * 128 + n]);
    }
}

// ---------- CSR build: histogram ----------
__global__ __launch_bounds__(256) void k_hist(
    const int* __restrict__ ei, unsigned int* __restrict__ cnt, int E, int N)
{
    int e = blockIdx.x * blockDim.x + threadIdx.x;
    int Et = E + N;
    if (e >= Et) return;
    int d = (e < E) ? ei[E + e] : (e - E);
    atomicAdd(&cnt[d], 1u);
}

// ---------- CSR build: per-block partial sums ----------
__global__ __launch_bounds__(256) void k_partsum(
    const unsigned int* __restrict__ cnt, unsigned int* __restrict__ bsum, int N)
{
    __shared__ unsigned int sm[4];
    int t = threadIdx.x;
    int i = blockIdx.x * 256 + t;
    unsigned int v = (i < N) ? cnt[i] : 0u;
#pragma unroll
    for (int off = 32; off > 0; off >>= 1) v += (unsigned int)__shfl_down((int)v, off, 64);
    if ((t & 63) == 0) sm[t >> 6] = v;
    __syncthreads();
    if (t == 0) bsum[blockIdx.x] = sm[0] + sm[1] + sm[2] + sm[3];
}

// ---------- CSR build: scan of block sums ----------
__global__ __launch_bounds__(256) void k_scanb(
    const unsigned int* __restrict__ bsum, unsigned int* __restrict__ boff,
    unsigned int* __restrict__ row, int nb2, int N, int Et)
{
    __shared__ unsigned int sm[256];
    int t = threadIdx.x;
    unsigned int v = (t < nb2) ? bsum[t] : 0u;
    sm[t] = v;
    __syncthreads();
#pragma unroll
    for (int off = 1; off < 256; off <<= 1) {
        unsigned int a = (t >= off) ? sm[t - off] : 0u;
        __syncthreads();
        sm[t] += a;
        __syncthreads();
    }
    if (t < nb2) boff[t] = sm[t] - v;
    if (t == 0) row[N] = (unsigned int)Et;
}

// ---------- CSR build: per-element exclusive scan ----------
__global__ __launch_bounds__(256) void k_scanw(
    const unsigned int* __restrict__ cnt, const unsigned int* __restrict__ boff,
    unsigned int* __restrict__ row, unsigned int* __restrict__ pos, int N)
{
    __shared__ unsigned int sm[256];
    int t = threadIdx.x;
    int i = blockIdx.x * 256 + t;
    unsigned int v = (i < N) ? cnt[i] : 0u;
    sm[t] = v;
    __syncthreads();
#pragma unroll
    for (int off = 1; off < 256; off <<= 1) {
        unsigned int a = (t >= off) ? sm[t - off] : 0u;
        __syncthreads();
        sm[t] += a;
        __syncthreads();
    }
    if (i < N) {
        unsigned int o = boff[blockIdx.x] + sm[t] - v;
        row[i] = o;
        pos[i] = o;
    }
}

// ---------- CSR build: scatter src indices ----------
__global__ __launch_bounds__(256) void k_scatter(
    const int* __restrict__ ei, unsigned int* __restrict__ pos,
    int* __restrict__ srcs, int E, int N)
{
    int e = blockIdx.x * blockDim.x + threadIdx.x;
    int Et = E + N;
    if (e >= Et) return;
    int s, d;
    if (e < E) { s = ei[e]; d = ei[E + e]; } else { s = d = e - E; }
    unsigned int p = atomicAdd(&pos[d], 1u);
    srcs[p] = s;
}

// ---------- K3: segment softmax + aggregation, one wave per dst ----------
__global__ __launch_bounds__(256) void k_agg(
    const unsigned int* __restrict__ row, const int* __restrict__ srcs,
    const float* __restrict__ a_src, const float* __restrict__ a_dst,
    const unsigned int* __restrict__ xhb,   // packed bf16 pairs, N*64 words
    float* __restrict__ aggN, int N)
{
    int w = threadIdx.x >> 6, lane = threadIdx.x & 63;
    int d = blockIdx.x * 4 + w;
    if (d >= N) return;
    int start = (int)row[d], end = (int)row[d + 1];

    // ---- pass 1: per-head max; edges distributed across 16 lane-groups ----
    int hm = lane & 3;
    float adm = a_dst[d * HEADS + hm];
    float m = -3.4e38f;
    for (int e = start + (lane >> 2); e < end; e += 16) {
        int s = srcs[e];
        float al = a_src[s * HEADS + hm] + adm;
        al = (al >= 0.f) ? al : NEG_SLOPE * al;
        m = fmaxf(m, al);
    }
#pragma unroll
    for (int off = 4; off < 64; off <<= 1)
        m = fmaxf(m, __shfl_xor(m, off, 64));

    // ---- pass 2: lane covers channels 2*lane, 2*lane+1; head = lane>>4 ----
    int h = lane >> 4;
    float mh  = __shfl(m, h, 64);
    float adh = __shfl(adm, h, 64);

    float den = 0.f, acc0 = 0.f, acc1 = 0.f;
    int s_cur = srcs[start];
    for (int e = start; e < end; ++e) {
        int s_next = (e + 1 < end) ? srcs[e + 1] : 0;
        float as = a_src[s_cur * HEADS + h];
        unsigned int u = xhb[(size_t)s_cur * 64 + lane];
        float al = as + adh;
        al = (al >= 0.f) ? al : NEG_SLOPE * al;
        float p = __expf(al - mh);
        den += p;
        acc0 += p * __uint_as_float(u << 16);
        acc1 += p * __uint_as_float(u & 0xFFFF0000u);
        s_cur = s_next;
    }
    float inv = 1.0f / den;
    float2 o; o.x = acc0 * inv; o.y = acc1 * inv;
    ((float2*)aggN)[(size_t)d * 64 + lane] = o;
}

// ---------- K4: bias+residual+LN2 + MFMA FFN + residual (32 nodes / 256 thr) ----------
#define SRST 132   // shres row stride (fp32)
#define ABST 144   // A_bf row stride (bf16) -> 288 B, 16B-aligned
#define HST  272   // hid_bf row stride (bf16) -> 544 B, 16B-aligned
__global__ __launch_bounds__(256) void k_final(
    const float* __restrict__ aggN,
    const float* __restrict__ x,
    const float* __restrict__ gat_b,
    const float* __restrict__ g2, const float* __restrict__ b2g,
    const unsigned short* __restrict__ wp1, const float* __restrict__ bb1,
    const unsigned short* __restrict__ wp2, const float* __restrict__ bb2,
    float* __restrict__ out, int N)
{
    __shared__ float shres[NPB * SRST];
    __shared__ __align__(16) unsigned short A_bf[NPB * ABST];
    __shared__ __align__(16) unsigned short hid_bf[NPB * HST];
    int t = threadIdx.x;
    int w = t >> 6, lane = t & 63;
    int quad = lane >> 4, l15 = lane & 15;
    int nbase = blockIdx.x * NPB;

    // ---- Phase A: o+bias+residual, LN2 -> A_bf (bf16), shres (fp32) ----
#pragma unroll
    for (int i = 0; i < 8; ++i) {
        int nn = w * 8 + i;
        int n = nbase + nn;
        float h0 = 0.f, h1 = 0.f;
        if (n < N) {
            h0 = aggN[n * DIN + lane]      + gat_b[lane]      + x[n * DIN + lane];
            h1 = aggN[n * DIN + 64 + lane] + gat_b[64 + lane] + x[n * DIN + 64 + lane];
        }
        float mean = wave_allsum(h0 + h1) * (1.0f / DIN);
        float d0 = h0 - mean, d1 = h1 - mean;
        float var = wave_allsum(d0 * d0 + d1 * d1) * (1.0f / DIN);
        float rstd = rsqrtf(var + LN_EPS);
        shres[nn * SRST + lane]      = h0;
        shres[nn * SRST + 64 + lane] = h1;
        A_bf[nn * ABST + lane]      = f2bf(d0 * rstd * g2[lane]      + b2g[lane]);
        A_bf[nn * ABST + 64 + lane] = f2bf(d1 * rstd * g2[64 + lane] + b2g[64 + lane]);
    }
    __syncthreads();

    // ---- Phase B: FFN1 (32x256 = A[32x128] @ w1[128x256]) + GELU -> hid_bf ----
    {
        int m_t = w & 1;
        int nt_base = (w >> 1) * 8;
        int arow = (m_t * 16 + l15) * ABST;
        bf16x8 afrag[4];
#pragma unroll
        for (int ks = 0; ks < 4; ++ks)
            afrag[ks] = *(const bf16x8*)&A_bf[arow + ks * 32 + quad * 8];
#pragma unroll
        for (int nt = 0; nt < 8; ++nt) {
            int tile = nt_base + nt;
            f32x4 acc = {0.f, 0.f, 0.f, 0.f};
#pragma unroll
            for (int ks = 0; ks < 4; ++ks) {
                bf16x8 bfrag = *(const bf16x8*)&wp1[(((tile * 4 + ks) * 64 + lane) << 3)];
                acc = __builtin_amdgcn_mfma_f32_16x16x32_bf16(afrag[ks], bfrag, acc, 0, 0, 0);
            }
            int col = tile * 16 + l15;
            float bias = bb1[col];
#pragma unroll
            for (int reg = 0; reg < 4; ++reg) {
                int m_local = m_t * 16 + quad * 4 + reg;
                float a = acc[reg] + bias;
                float g = 0.5f * a * (1.0f + erff(a * 0.70710678118654752f));
                hid_bf[m_local * HST + col] = f2bf(g);
            }
        }
    }
    __syncthreads();

    // ---- Phase C: FFN2 (32x128 = hid[32x256] @ w2[256x128]) + residual ----
    {
        int m_t = w & 1;
        int nt_base = (w >> 1) * 4;
        int arow = (m_t * 16 + l15) * HST;
        bf16x8 afrag[8];
#pragma unroll
        for (int ks = 0; ks < 8; ++ks)
            afrag[ks] = *(const bf16x8*)&hid_bf[arow + ks * 32 + quad * 8];
#pragma unroll
        for (int nt = 0; nt < 4; ++nt) {
            int tile = nt_base + nt;
            f32x4 acc = {0.f, 0.f, 0.f, 0.f};
#pragma unroll
            for (int ks = 0; ks < 8; ++ks) {
                bf16x8 bfrag = *(const bf16x8*)&wp2[(((tile * 8 + ks) * 64 + lane) << 3)];
                acc = __builtin_amdgcn_mfma_f32_16x16x32_bf16(afrag[ks], bfrag, acc, 0, 0, 0);
            }
            int j = tile * 16 + l15;
            float bias = bb2[j];
#pragma unroll
            for (int reg = 0; reg < 4; ++reg) {
                int m_local = m_t * 16 + quad * 4 + reg;
                int n = nbase + m_local;
                if (n < N)
                    out[(size_t)n * DIN + j] = shres[m_local * SRST + j] + acc[reg] + bias;
            }
        }
    }
}

extern "C" void kernel_launch(void* const* d_in, const int* in_sizes, int n_in,
                              void* d_out, int out_size, void* d_ws, size_t ws_size,
                              hipStream_t stream) {
    const float* x       = (const float*)d_in[0];
    const int*   ei      = (const int*)d_in[1];
    const float* ln1_g   = (const float*)d_in[2];
    const float* ln1_b   = (const float*)d_in[3];
    const float* W       = (const float*)d_in[4];
    const float* att_src = (const float*)d_in[5];
    const float* att_dst = (const float*)d_in[6];
    const float* gat_b   = (const float*)d_in[7];
    const float* ln2_g   = (const float*)d_in[8];
    const float* ln2_b   = (const float*)d_in[9];
    const float* w1      = (const float*)d_in[10];
    const float* b1      = (const float*)d_in[11];
    const float* w2      = (const float*)d_in[12];
    const float* b2      = (const float*)d_in[13];
    float* out = (float*)d_out;

    const int N = in_sizes[0] / DIN;
    const int E = in_sizes[1] / 2;
    const int Et = E + N;

    // workspace layout:
    //   u16 wp1[32768] | u16 wp2[32768]           (16B-aligned at ws start)
    //   u32 cnt[N] (zeroed) | u32 row[N+1] | u32 pos[N] | u32 bsum[256] | u32 boff[256]
    //   int srcs[Et] | u16 xhb[N*128] | f32 a_src[N*4] | f32 a_dst[N*4] | f32 aggN[N*128]
    unsigned short* wp1 = (unsigned short*)d_ws;
    unsigned short* wp2 = wp1 + 32768;
    unsigned int* cnt  = (unsigned int*)(wp2 + 32768);
    unsigned int* row  = cnt + N;
    unsigned int* pos  = row + N + 1;
    unsigned int* bsum = pos + N;
    unsigned int* boff = bsum + 256;
    int*           srcs = (int*)(boff + 256);
    unsigned short* xhb = (unsigned short*)(srcs + Et);
    float*        a_src = (float*)(xhb + (size_t)N * DIN);
    float*        a_dst = a_src + (size_t)N * HEADS;
    float*        aggN  = a_dst + (size_t)N * HEADS;

    hipMemsetAsync(cnt, 0, (size_t)N * sizeof(unsigned int), stream);

    k_pack<<<256, 256, 0, stream>>>(w1, w2, wp1, wp2);

    int nblocks = (N + NB - 1) / NB;
    k_ln_proj<<<nblocks, 256, 0, stream>>>(x, ln1_g, ln1_b, W, att_src, att_dst, xhb, a_src, a_dst, N);

    int eblocks = (Et + 255) / 256;
    int nb2 = (N + 255) / 256;   // must be <= 256 (N <= 65536)
    k_hist<<<eblocks, 256, 0, stream>>>(ei, cnt, E, N);
    k_partsum<<<nb2, 256, 0, stream>>>(cnt, bsum, N);
    k_scanb<<<1, 256, 0, stream>>>(bsum, boff, row, nb2, N, Et);
    k_scanw<<<nb2, 256, 0, stream>>>(cnt, boff, row, pos, N);
    k_scatter<<<eblocks, 256, 0, stream>>>(ei, pos, srcs, E, N);

    int ablocks = (N + 3) / 4;
    k_agg<<<ablocks, 256, 0, stream>>>(row, srcs, a_src, a_dst, (const unsigned int*)xhb, aggN, N);

    int nblocks4 = (N + NPB - 1) / NPB;
    k_final<<<nblocks4, 256, 0, stream>>>(aggN, x, gat_b, ln2_g, ln2_b, wp1, b1, wp2, b2, out, N);
}

// Round 7
// 346.513 us; speedup vs baseline: 3.3530x; 1.1379x over previous
//
#include <hip/hip_runtime.h>

#define DIN 128
#define HEADS 4
#define CPH 32
#define NEG_SLOPE 0.2f
#define LN_EPS 1e-5f
#define NB 8    // nodes per block in K1
#define NPB 32  // nodes per block in K4 (MFMA)

typedef short bf16x8 __attribute__((ext_vector_type(8)));
typedef float f32x4 __attribute__((ext_vector_type(4)));

__device__ __forceinline__ float wave_allsum(float v) {
#pragma unroll
    for (int off = 32; off > 0; off >>= 1) v += __shfl_down(v, off, 64);
    return __shfl(v, 0, 64);
}

// round-to-nearest-even fp32 -> bf16 bits
__device__ __forceinline__ unsigned short f2bf(float f) {
    unsigned int b = __float_as_uint(f);
    b += 0x7FFFu + ((b >> 16) & 1u);
    return (unsigned short)(b >> 16);
}

// ---------- K1: LN1 + projection + attention logits (8 nodes / 256 thr) ----------
__global__ __launch_bounds__(256) void k_ln_proj(
    const float* __restrict__ x,
    const float* __restrict__ g1, const float* __restrict__ b1,
    const float* __restrict__ W,
    const float* __restrict__ att_src, const float* __restrict__ att_dst,
    unsigned short* __restrict__ xhb, float* __restrict__ a_src, float* __restrict__ a_dst, int N)
{
    __shared__ float sh[NB][DIN];   // normalized activations
    __shared__ float sxh[NB][DIN];  // projected
    int t = threadIdx.x;
    int wave = t >> 6, lane = t & 63;
    int nbase = blockIdx.x * NB;

#pragma unroll
    for (int i = 0; i < 2; ++i) {
        int nn = wave * 2 + i;
        int n = nbase + nn;
        float x0 = 0.f, x1 = 0.f;
        if (n < N) { x0 = x[n * DIN + lane]; x1 = x[n * DIN + 64 + lane]; }
        float mean = wave_allsum(x0 + x1) * (1.0f / DIN);
        float d0 = x0 - mean, d1 = x1 - mean;
        float var = wave_allsum(d0 * d0 + d1 * d1) * (1.0f / DIN);
        float rstd = rsqrtf(var + LN_EPS);
        sh[nn][lane]      = d0 * rstd * g1[lane]      + b1[lane];
        sh[nn][64 + lane] = d1 * rstd * g1[64 + lane] + b1[64 + lane];
    }
    __syncthreads();

    // projection; thread t: column j, nodes half*4..half*4+3
    int j = t & (DIN - 1), half = t >> 7;
    int nb0 = half * 4;
    float acc0 = 0.f, acc1 = 0.f, acc2 = 0.f, acc3 = 0.f;
#pragma unroll 4
    for (int k = 0; k < DIN; ++k) {
        float w = W[k * DIN + j];
        acc0 += sh[nb0 + 0][k] * w;
        acc1 += sh[nb0 + 1][k] * w;
        acc2 += sh[nb0 + 2][k] * w;
        acc3 += sh[nb0 + 3][k] * w;
    }
    sxh[nb0 + 0][j] = acc0;
    sxh[nb0 + 1][j] = acc1;
    sxh[nb0 + 2][j] = acc2;
    sxh[nb0 + 3][j] = acc3;
    {
        int n0 = nbase + nb0;
        if (n0 + 0 < N) xhb[(size_t)(n0 + 0) * DIN + j] = f2bf(acc0);
        if (n0 + 1 < N) xhb[(size_t)(n0 + 1) * DIN + j] = f2bf(acc1);
        if (n0 + 2 < N) xhb[(size_t)(n0 + 2) * DIN + j] = f2bf(acc2);
        if (n0 + 3 < N) xhb[(size_t)(n0 + 3) * DIN + j] = f2bf(acc3);
    }
    __syncthreads();

    // attention logits. t = nn(3b) | h(2b) | sub(3b)
    {
        int nn = t >> 5, h = (t >> 3) & 3, sub = t & 7;
        float s1 = 0.f, s2 = 0.f;
#pragma unroll
        for (int i = 0; i < 4; ++i) {
            int c = h * CPH + sub * 4 + i;
            float v = sxh[nn][c];
            s1 += v * att_src[c];
            s2 += v * att_dst[c];
        }
        s1 += __shfl_down(s1, 4, 64); s2 += __shfl_down(s2, 4, 64);
        s1 += __shfl_down(s1, 2, 64); s2 += __shfl_down(s2, 2, 64);
        s1 += __shfl_down(s1, 1, 64); s2 += __shfl_down(s2, 1, 64);
        int n = nbase + nn;
        if (sub == 0 && n < N) {
            a_src[n * HEADS + h] = s1;
            a_dst[n * HEADS + h] = s2;
        }
    }
}

// ---------- pack w1/w2 into bf16 MFMA B-fragment order ----------
__global__ __launch_bounds__(256) void k_pack(
    const float* __restrict__ w1, const float* __restrict__ w2,
    unsigned short* __restrict__ wp1, unsigned short* __restrict__ wp2)
{
    int idx = blockIdx.x * 256 + threadIdx.x;
    if (idx < 32768) {
        int j = idx & 7, lane = (idx >> 3) & 63, tk = idx >> 9;
        int ks = tk & 3, tile = tk >> 2;
        int k = ks * 32 + ((lane >> 4) << 3) + j;
        int n = tile * 16 + (lane & 15);
        wp1[idx] = f2bf(w1[k * 256 + n]);
    } else {
        int i2 = idx - 32768;
        int j = i2 & 7, lane = (i2 >> 3) & 63, tk = i2 >> 9;
        int ks = tk & 7, tile = tk >> 3;
        int k = ks * 32 + ((lane >> 4) << 3) + j;
        int n = tile * 16 + (lane & 15);
        wp2[i2] = f2bf(w2[k * 128 + n]);
    }
}

// ---------- CSR build: histogram ----------
__global__ __launch_bounds__(256) void k_hist(
    const int* __restrict__ ei, unsigned int* __restrict__ cnt, int E, int N)
{
    int e = blockIdx.x * blockDim.x + threadIdx.x;
    int Et = E + N;
    if (e >= Et) return;
    int d = (e < E) ? ei[E + e] : (e - E);
    atomicAdd(&cnt[d], 1u);
}

// ---------- CSR build: per-block partial sums ----------
__global__ __launch_bounds__(256) void k_partsum(
    const unsigned int* __restrict__ cnt, unsigned int* __restrict__ bsum, int N)
{
    __shared__ unsigned int sm[4];
    int t = threadIdx.x;
    int i = blockIdx.x * 256 + t;
    unsigned int v = (i < N) ? cnt[i] : 0u;
#pragma unroll
    for (int off = 32; off > 0; off >>= 1) v += (unsigned int)__shfl_down((int)v, off, 64);
    if ((t & 63) == 0) sm[t >> 6] = v;
    __syncthreads();
    if (t == 0) bsum[blockIdx.x] = sm[0] + sm[1] + sm[2] + sm[3];
}

// ---------- CSR build: scan of block sums ----------
__global__ __launch_bounds__(256) void k_scanb(
    const unsigned int* __restrict__ bsum, unsigned int* __restrict__ boff,
    unsigned int* __restrict__ row, int nb2, int N, int Et)
{
    __shared__ unsigned int sm[256];
    int t = threadIdx.x;
    unsigned int v = (t < nb2) ? bsum[t] : 0u;
    sm[t] = v;
    __syncthreads();
#pragma unroll
    for (int off = 1; off < 256; off <<= 1) {
        unsigned int a = (t >= off) ? sm[t - off] : 0u;
        __syncthreads();
        sm[t] += a;
        __syncthreads();
    }
    if (t < nb2) boff[t] = sm[t] - v;
    if (t == 0) row[N] = (unsigned int)Et;
}

// ---------- CSR build: per-element exclusive scan ----------
__global__ __launch_bounds__(256) void k_scanw(
    const unsigned int* __restrict__ cnt, const unsigned int* __restrict__ boff,
    unsigned int* __restrict__ row, unsigned int* __restrict__ pos, int N)
{
    __shared__ unsigned int sm[256];
    int t = threadIdx.x;
    int i = blockIdx.x * 256 + t;
    unsigned int v = (i < N) ? cnt[i] : 0u;
    sm[t] = v;
    __syncthreads();
#pragma unroll
    for (int off = 1; off < 256; off <<= 1) {
        unsigned int a = (t >= off) ? sm[t - off] : 0u;
        __syncthreads();
        sm[t] += a;
        __syncthreads();
    }
    if (i < N) {
        unsigned int o = boff[blockIdx.x] + sm[t] - v;
        row[i] = o;
        pos[i] = o;
    }
}

// ---------- CSR build: scatter src indices ----------
__global__ __launch_bounds__(256) void k_scatter(
    const int* __restrict__ ei, unsigned int* __restrict__ pos,
    int* __restrict__ srcs, int E, int N)
{
    int e = blockIdx.x * blockDim.x + threadIdx.x;
    int Et = E + N;
    if (e >= Et) return;
    int s, d;
    if (e < E) { s = ei[e]; d = ei[E + e]; } else { s = d = e - E; }
    unsigned int p = atomicAdd(&pos[d], 1u);
    srcs[p] = s;
}

// ---------- K3: segment softmax + aggregation, one wave per dst ----------
// No max-subtraction: exp(al)/sum(exp(al)) is mathematically identical to the
// max-shifted version, and logits here are O(8) max -> no overflow risk in fp32.
__global__ __launch_bounds__(256) void k_agg(
    const unsigned int* __restrict__ row, const int* __restrict__ srcs,
    const float* __restrict__ a_src, const float* __restrict__ a_dst,
    const unsigned int* __restrict__ xhb,   // packed bf16 pairs, N*64 words
    float* __restrict__ aggN, int N)
{
    int w = threadIdx.x >> 6, lane = threadIdx.x & 63;
    int d = blockIdx.x * 4 + w;
    if (d >= N) return;
    int start = (int)row[d], end = (int)row[d + 1];
    int h = lane >> 4;                 // head for this lane's channel pair
    float adh = a_dst[d * HEADS + h];

    float den = 0.f, acc0 = 0.f, acc1 = 0.f;
    int e = start;
    // unroll x4: batch the index loads, then 8 independent gathers in flight
    for (; e + 4 <= end; e += 4) {
        int s0 = srcs[e], s1 = srcs[e + 1], s2 = srcs[e + 2], s3 = srcs[e + 3];
        float as0 = a_src[s0 * HEADS + h];
        float as1 = a_src[s1 * HEADS + h];
        float as2 = a_src[s2 * HEADS + h];
        float as3 = a_src[s3 * HEADS + h];
        unsigned int u0 = xhb[(size_t)s0 * 64 + lane];
        unsigned int u1 = xhb[(size_t)s1 * 64 + lane];
        unsigned int u2 = xhb[(size_t)s2 * 64 + lane];
        unsigned int u3 = xhb[(size_t)s3 * 64 + lane];
        float al0 = as0 + adh; al0 = (al0 >= 0.f) ? al0 : NEG_SLOPE * al0;
        float al1 = as1 + adh; al1 = (al1 >= 0.f) ? al1 : NEG_SLOPE * al1;
        float al2 = as2 + adh; al2 = (al2 >= 0.f) ? al2 : NEG_SLOPE * al2;
        float al3 = as3 + adh; al3 = (al3 >= 0.f) ? al3 : NEG_SLOPE * al3;
        float p0 = __expf(al0), p1 = __expf(al1), p2 = __expf(al2), p3 = __expf(al3);
        den += (p0 + p1) + (p2 + p3);
        acc0 += p0 * __uint_as_float(u0 << 16);
        acc1 += p0 * __uint_as_float(u0 & 0xFFFF0000u);
        acc0 += p1 * __uint_as_float(u1 << 16);
        acc1 += p1 * __uint_as_float(u1 & 0xFFFF0000u);
        acc0 += p2 * __uint_as_float(u2 << 16);
        acc1 += p2 * __uint_as_float(u2 & 0xFFFF0000u);
        acc0 += p3 * __uint_as_float(u3 << 16);
        acc1 += p3 * __uint_as_float(u3 & 0xFFFF0000u);
    }
    for (; e < end; ++e) {
        int s = srcs[e];
        float as = a_src[s * HEADS + h];
        unsigned int u = xhb[(size_t)s * 64 + lane];
        float al = as + adh; al = (al >= 0.f) ? al : NEG_SLOPE * al;
        float p = __expf(al);
        den += p;
        acc0 += p * __uint_as_float(u << 16);
        acc1 += p * __uint_as_float(u & 0xFFFF0000u);
    }
    float inv = 1.0f / den;
    float2 o; o.x = acc0 * inv; o.y = acc1 * inv;
    ((float2*)aggN)[(size_t)d * 64 + lane] = o;
}

// ---------- K4: bias+residual+LN2 + MFMA FFN + residual (32 nodes / 256 thr) ----------
#define SRST 132   // shres row stride (fp32)
#define ABST 144   // A_bf row stride (bf16) -> 288 B, 16B-aligned
#define HST  272   // hid_bf row stride (bf16) -> 544 B, 16B-aligned
__global__ __launch_bounds__(256) void k_final(
    const float* __restrict__ aggN,
    const float* __restrict__ x,
    const float* __restrict__ gat_b,
    const float* __restrict__ g2, const float* __restrict__ b2g,
    const unsigned short* __restrict__ wp1, const float* __restrict__ bb1,
    const unsigned short* __restrict__ wp2, const float* __restrict__ bb2,
    float* __restrict__ out, int N)
{
    __shared__ float shres[NPB * SRST];
    __shared__ __align__(16) unsigned short A_bf[NPB * ABST];
    __shared__ __align__(16) unsigned short hid_bf[NPB * HST];
    int t = threadIdx.x;
    int w = t >> 6, lane = t & 63;
    int quad = lane >> 4, l15 = lane & 15;
    int nbase = blockIdx.x * NPB;

    // ---- Phase A: o+bias+residual, LN2 -> A_bf (bf16), shres (fp32) ----
#pragma unroll
    for (int i = 0; i < 8; ++i) {
        int nn = w * 8 + i;
        int n = nbase + nn;
        float h0 = 0.f, h1 = 0.f;
        if (n < N) {
            h0 = aggN[n * DIN + lane]      + gat_b[lane]      + x[n * DIN + lane];
            h1 = aggN[n * DIN + 64 + lane] + gat_b[64 + lane] + x[n * DIN + 64 + lane];
        }
        float mean = wave_allsum(h0 + h1) * (1.0f / DIN);
        float d0 = h0 - mean, d1 = h1 - mean;
        float var = wave_allsum(d0 * d0 + d1 * d1) * (1.0f / DIN);
        float rstd = rsqrtf(var + LN_EPS);
        shres[nn * SRST + lane]      = h0;
        shres[nn * SRST + 64 + lane] = h1;
        A_bf[nn * ABST + lane]      = f2bf(d0 * rstd * g2[lane]      + b2g[lane]);
        A_bf[nn * ABST + 64 + lane] = f2bf(d1 * rstd * g2[64 + lane] + b2g[64 + lane]);
    }
    __syncthreads();

    // ---- Phase B: FFN1 (32x256 = A[32x128] @ w1[128x256]) + GELU -> hid_bf ----
    {
        int m_t = w & 1;
        int nt_base = (w >> 1) * 8;
        int arow = (m_t * 16 + l15) * ABST;
        bf16x8 afrag[4];
#pragma unroll
        for (int ks = 0; ks < 4; ++ks)
            afrag[ks] = *(const bf16x8*)&A_bf[arow + ks * 32 + quad * 8];
#pragma unroll
        for (int nt = 0; nt < 8; ++nt) {
            int tile = nt_base + nt;
            f32x4 acc = {0.f, 0.f, 0.f, 0.f};
#pragma unroll
            for (int ks = 0; ks < 4; ++ks) {
                bf16x8 bfrag = *(const bf16x8*)&wp1[(((tile * 4 + ks) * 64 + lane) << 3)];
                acc = __builtin_amdgcn_mfma_f32_16x16x32_bf16(afrag[ks], bfrag, acc, 0, 0, 0);
            }
            int col = tile * 16 + l15;
            float bias = bb1[col];
#pragma unroll
            for (int reg = 0; reg < 4; ++reg) {
                int m_local = m_t * 16 + quad * 4 + reg;
                float a = acc[reg] + bias;
                float g = 0.5f * a * (1.0f + erff(a * 0.70710678118654752f));
                hid_bf[m_local * HST + col] = f2bf(g);
            }
        }
    }
    __syncthreads();

    // ---- Phase C: FFN2 (32x128 = hid[32x256] @ w2[256x128]) + residual ----
    {
        int m_t = w & 1;
        int nt_base = (w >> 1) * 4;
        int arow = (m_t * 16 + l15) * HST;
        bf16x8 afrag[8];
#pragma unroll
        for (int ks = 0; ks < 8; ++ks)
            afrag[ks] = *(const bf16x8*)&hid_bf[arow + ks * 32 + quad * 8];
#pragma unroll
        for (int nt = 0; nt < 4; ++nt) {
            int tile = nt_base + nt;
            f32x4 acc = {0.f, 0.f, 0.f, 0.f};
#pragma unroll
            for (int ks = 0; ks < 8; ++ks) {
                bf16x8 bfrag = *(const bf16x8*)&wp2[(((tile * 8 + ks) * 64 + lane) << 3)];
                acc = __builtin_amdgcn_mfma_f32_16x16x32_bf16(afrag[ks], bfrag, acc, 0, 0, 0);
            }
            int j = tile * 16 + l15;
            float bias = bb2[j];
#pragma unroll
            for (int reg = 0; reg < 4; ++reg) {
                int m_local = m_t * 16 + quad * 4 + reg;
                int n = nbase + m_local;
                if (n < N)
                    out[(size_t)n * DIN + j] = shres[m_local * SRST + j] + acc[reg] + bias;
            }
        }
    }
}

extern "C" void kernel_launch(void* const* d_in, const int* in_sizes, int n_in,
                              void* d_out, int out_size, void* d_ws, size_t ws_size,
                              hipStream_t stream) {
    const float* x       = (const float*)d_in[0];
    const int*   ei      = (const int*)d_in[1];
    const float* ln1_g   = (const float*)d_in[2];
    const float* ln1_b   = (const float*)d_in[3];
    const float* W       = (const float*)d_in[4];
    const float* att_src = (const float*)d_in[5];
    const float* att_dst = (const float*)d_in[6];
    const float* gat_b   = (const float*)d_in[7];
    const float* ln2_g   = (const float*)d_in[8];
    const float* ln2_b   = (const float*)d_in[9];
    const float* w1      = (const float*)d_in[10];
    const float* b1      = (const float*)d_in[11];
    const float* w2      = (const float*)d_in[12];
    const float* b2      = (const float*)d_in[13];
    float* out = (float*)d_out;

    const int N = in_sizes[0] / DIN;
    const int E = in_sizes[1] / 2;
    const int Et = E + N;

    // workspace layout:
    //   u16 wp1[32768] | u16 wp2[32768]           (16B-aligned at ws start)
    //   u32 cnt[N] (zeroed) | u32 row[N+1] | u32 pos[N] | u32 bsum[256] | u32 boff[256]
    //   int srcs[Et] | u16 xhb[N*128] | f32 a_src[N*4] | f32 a_dst[N*4] | f32 aggN[N*128]
    unsigned short* wp1 = (unsigned short*)d_ws;
    unsigned short* wp2 = wp1 + 32768;
    unsigned int* cnt  = (unsigned int*)(wp2 + 32768);
    unsigned int* row  = cnt + N;
    unsigned int* pos  = row + N + 1;
    unsigned int* bsum = pos + N;
    unsigned int* boff = bsum + 256;
    int*           srcs = (int*)(boff + 256);
    unsigned short* xhb = (unsigned short*)(srcs + Et);
    float*        a_src = (float*)(xhb + (size_t)N * DIN);
    float*        a_dst = a_src + (size_t)N * HEADS;
    float*        aggN  = a_dst + (size_t)N * HEADS;

    hipMemsetAsync(cnt, 0, (size_t)N * sizeof(unsigned int), stream);

    k_pack<<<256, 256, 0, stream>>>(w1, w2, wp1, wp2);

    int nblocks = (N + NB - 1) / NB;
    k_ln_proj<<<nblocks, 256, 0, stream>>>(x, ln1_g, ln1_b, W, att_src, att_dst, xhb, a_src, a_dst, N);

    int eblocks = (Et + 255) / 256;
    int nb2 = (N + 255) / 256;   // must be <= 256 (N <= 65536)
    k_hist<<<eblocks, 256, 0, stream>>>(ei, cnt, E, N);
    k_partsum<<<nb2, 256, 0, stream>>>(cnt, bsum, N);
    k_scanb<<<1, 256, 0, stream>>>(bsum, boff, row, nb2, N, Et);
    k_scanw<<<nb2, 256, 0, stream>>>(cnt, boff, row, pos, N);
    k_scatter<<<eblocks, 256, 0, stream>>>(ei, pos, srcs, E, N);

    int ablocks = (N + 3) / 4;
    k_agg<<<ablocks, 256, 0, stream>>>(row, srcs, a_src, a_dst, (const unsigned int*)xhb, aggN, N);

    int nblocks4 = (N + NPB - 1) / NPB;
    k_final<<<nblocks4, 256, 0, stream>>>(aggN, x, gat_b, ln2_g, ln2_b, wp1, b1, wp2, b2, out, N);
}

// Round 8
// 306.947 us; speedup vs baseline: 3.7852x; 1.1289x over previous
//
#include <hip/hip_runtime.h>

#define DIN 128
#define HEADS 4
#define CPH 32
#define NEG_SLOPE 0.2f
#define LN_EPS 1e-5f
#define NB 8    // nodes per block in K1
#define NPB 16  // nodes per block in K4 (MFMA)
#define CS 4096 // edges per chunk in hist/scatter

typedef short bf16x8 __attribute__((ext_vector_type(8)));
typedef float f32x4 __attribute__((ext_vector_type(4)));

__device__ __forceinline__ float wave_allsum(float v) {
#pragma unroll
    for (int off = 32; off > 0; off >>= 1) v += __shfl_down(v, off, 64);
    return __shfl(v, 0, 64);
}

// round-to-nearest-even fp32 -> bf16 bits
__device__ __forceinline__ unsigned short f2bf(float f) {
    unsigned int b = __float_as_uint(f);
    b += 0x7FFFu + ((b >> 16) & 1u);
    return (unsigned short)(b >> 16);
}

// ---------- K1: LN1 + projection + attention logits (8 nodes / 256 thr) ----------
__global__ __launch_bounds__(256) void k_ln_proj(
    const float* __restrict__ x,
    const float* __restrict__ g1, const float* __restrict__ b1,
    const float* __restrict__ W,
    const float* __restrict__ att_src, const float* __restrict__ att_dst,
    unsigned short* __restrict__ xhb, float* __restrict__ a_src, float* __restrict__ a_dst, int N)
{
    __shared__ float sh[NB][DIN];   // normalized activations
    __shared__ float sxh[NB][DIN];  // projected
    int t = threadIdx.x;
    int wave = t >> 6, lane = t & 63;
    int nbase = blockIdx.x * NB;

#pragma unroll
    for (int i = 0; i < 2; ++i) {
        int nn = wave * 2 + i;
        int n = nbase + nn;
        float x0 = 0.f, x1 = 0.f;
        if (n < N) { x0 = x[n * DIN + lane]; x1 = x[n * DIN + 64 + lane]; }
        float mean = wave_allsum(x0 + x1) * (1.0f / DIN);
        float d0 = x0 - mean, d1 = x1 - mean;
        float var = wave_allsum(d0 * d0 + d1 * d1) * (1.0f / DIN);
        float rstd = rsqrtf(var + LN_EPS);
        sh[nn][lane]      = d0 * rstd * g1[lane]      + b1[lane];
        sh[nn][64 + lane] = d1 * rstd * g1[64 + lane] + b1[64 + lane];
    }
    __syncthreads();

    // projection; thread t: column j, nodes half*4..half*4+3
    int j = t & (DIN - 1), half = t >> 7;
    int nb0 = half * 4;
    float acc0 = 0.f, acc1 = 0.f, acc2 = 0.f, acc3 = 0.f;
#pragma unroll 4
    for (int k = 0; k < DIN; ++k) {
        float w = W[k * DIN + j];
        acc0 += sh[nb0 + 0][k] * w;
        acc1 += sh[nb0 + 1][k] * w;
        acc2 += sh[nb0 + 2][k] * w;
        acc3 += sh[nb0 + 3][k] * w;
    }
    sxh[nb0 + 0][j] = acc0;
    sxh[nb0 + 1][j] = acc1;
    sxh[nb0 + 2][j] = acc2;
    sxh[nb0 + 3][j] = acc3;
    {
        int n0 = nbase + nb0;
        if (n0 + 0 < N) xhb[(size_t)(n0 + 0) * DIN + j] = f2bf(acc0);
        if (n0 + 1 < N) xhb[(size_t)(n0 + 1) * DIN + j] = f2bf(acc1);
        if (n0 + 2 < N) xhb[(size_t)(n0 + 2) * DIN + j] = f2bf(acc2);
        if (n0 + 3 < N) xhb[(size_t)(n0 + 3) * DIN + j] = f2bf(acc3);
    }
    __syncthreads();

    // attention logits. t = nn(3b) | h(2b) | sub(3b)
    {
        int nn = t >> 5, h = (t >> 3) & 3, sub = t & 7;
        float s1 = 0.f, s2 = 0.f;
#pragma unroll
        for (int i = 0; i < 4; ++i) {
            int c = h * CPH + sub * 4 + i;
            float v = sxh[nn][c];
            s1 += v * att_src[c];
            s2 += v * att_dst[c];
        }
        s1 += __shfl_down(s1, 4, 64); s2 += __shfl_down(s2, 4, 64);
        s1 += __shfl_down(s1, 2, 64); s2 += __shfl_down(s2, 2, 64);
        s1 += __shfl_down(s1, 1, 64); s2 += __shfl_down(s2, 1, 64);
        int n = nbase + nn;
        if (sub == 0 && n < N) {
            a_src[n * HEADS + h] = s1;
            a_dst[n * HEADS + h] = s2;
        }
    }
}

// ---------- pack w1/w2 into bf16 MFMA B-fragment order ----------
__global__ __launch_bounds__(256) void k_pack(
    const float* __restrict__ w1, const float* __restrict__ w2,
    unsigned short* __restrict__ wp1, unsigned short* __restrict__ wp2)
{
    int idx = blockIdx.x * 256 + threadIdx.x;
    if (idx < 32768) {
        int j = idx & 7, lane = (idx >> 3) & 63, tk = idx >> 9;
        int ks = tk & 3, tile = tk >> 2;
        int k = ks * 32 + ((lane >> 4) << 3) + j;
        int n = tile * 16 + (lane & 15);
        wp1[idx] = f2bf(w1[k * 256 + n]);
    } else {
        int i2 = idx - 32768;
        int j = i2 & 7, lane = (i2 >> 3) & 63, tk = i2 >> 9;
        int ks = tk & 7, tile = tk >> 3;
        int k = ks * 32 + ((lane >> 4) << 3) + j;
        int n = tile * 16 + (lane & 15);
        wp2[i2] = f2bf(w2[k * 128 + n]);
    }
}

// ---------- CSR build: histogram, XCD-partitioned by dst range ----------
// block b: xcd = b&7 handles dsts [xcd*Nper, min((xcd+1)*Nper,N)); chunk = b>>3
__global__ __launch_bounds__(256) void k_hist(
    const int* __restrict__ ei, unsigned int* __restrict__ cnt, int E, int N, int Nper)
{
    int xcd = blockIdx.x & 7, chunk = blockIdx.x >> 3;
    int lo = xcd * Nper, hi = min(lo + Nper, N);
    int Et = E + N;
    int base = chunk * CS + threadIdx.x;
#pragma unroll
    for (int i = 0; i < CS / 256; ++i) {
        int e = base + i * 256;
        if (e >= Et) break;
        int d = (e < E) ? ei[E + e] : (e - E);
        if (d >= lo && d < hi) atomicAdd(&cnt[d], 1u);
    }
}

// ---------- CSR build: per-block partial sums ----------
__global__ __launch_bounds__(256) void k_partsum(
    const unsigned int* __restrict__ cnt, unsigned int* __restrict__ bsum, int N)
{
    __shared__ unsigned int sm[4];
    int t = threadIdx.x;
    int i = blockIdx.x * 256 + t;
    unsigned int v = (i < N) ? cnt[i] : 0u;
#pragma unroll
    for (int off = 32; off > 0; off >>= 1) v += (unsigned int)__shfl_down((int)v, off, 64);
    if ((t & 63) == 0) sm[t >> 6] = v;
    __syncthreads();
    if (t == 0) bsum[blockIdx.x] = sm[0] + sm[1] + sm[2] + sm[3];
}

// ---------- CSR build: scan of block sums ----------
__global__ __launch_bounds__(256) void k_scanb(
    const unsigned int* __restrict__ bsum, unsigned int* __restrict__ boff,
    unsigned int* __restrict__ row, int nb2, int N, int Et)
{
    __shared__ unsigned int sm[256];
    int t = threadIdx.x;
    unsigned int v = (t < nb2) ? bsum[t] : 0u;
    sm[t] = v;
    __syncthreads();
#pragma unroll
    for (int off = 1; off < 256; off <<= 1) {
        unsigned int a = (t >= off) ? sm[t - off] : 0u;
        __syncthreads();
        sm[t] += a;
        __syncthreads();
    }
    if (t < nb2) boff[t] = sm[t] - v;
    if (t == 0) row[N] = (unsigned int)Et;
}

// ---------- CSR build: per-element exclusive scan ----------
__global__ __launch_bounds__(256) void k_scanw(
    const unsigned int* __restrict__ cnt, const unsigned int* __restrict__ boff,
    unsigned int* __restrict__ row, unsigned int* __restrict__ pos, int N)
{
    __shared__ unsigned int sm[256];
    int t = threadIdx.x;
    int i = blockIdx.x * 256 + t;
    unsigned int v = (i < N) ? cnt[i] : 0u;
    sm[t] = v;
    __syncthreads();
#pragma unroll
    for (int off = 1; off < 256; off <<= 1) {
        unsigned int a = (t >= off) ? sm[t - off] : 0u;
        __syncthreads();
        sm[t] += a;
        __syncthreads();
    }
    if (i < N) {
        unsigned int o = boff[blockIdx.x] + sm[t] - v;
        row[i] = o;
        pos[i] = o;
    }
}

// ---------- CSR build: scatter src indices, XCD-partitioned by dst range ----------
// Each srcs[] line is written by exactly one dst range -> one XCD -> full-line
// writebacks instead of 64B-per-4B masked HBM writes.
__global__ __launch_bounds__(256) void k_scatter(
    const int* __restrict__ ei, unsigned int* __restrict__ pos,
    int* __restrict__ srcs, int E, int N, int Nper)
{
    int xcd = blockIdx.x & 7, chunk = blockIdx.x >> 3;
    int lo = xcd * Nper, hi = min(lo + Nper, N);
    int Et = E + N;
    int base = chunk * CS + threadIdx.x;
#pragma unroll
    for (int i = 0; i < CS / 256; ++i) {
        int e = base + i * 256;
        if (e >= Et) break;
        int d = (e < E) ? ei[E + e] : (e - E);
        if (d >= lo && d < hi) {
            int s = (e < E) ? ei[e] : d;
            unsigned int p = atomicAdd(&pos[d], 1u);
            srcs[p] = s;
        }
    }
}

// ---------- K3: segment softmax + aggregation, one wave per dst ----------
// No max-subtraction: exp(al)/sum(exp(al)) is mathematically identical to the
// max-shifted version, and logits here are O(8) max -> no overflow risk in fp32.
__global__ __launch_bounds__(256) void k_agg(
    const unsigned int* __restrict__ row, const int* __restrict__ srcs,
    const float* __restrict__ a_src, const float* __restrict__ a_dst,
    const unsigned int* __restrict__ xhb,   // packed bf16 pairs, N*64 words
    float* __restrict__ aggN, int N)
{
    int w = threadIdx.x >> 6, lane = threadIdx.x & 63;
    int d = blockIdx.x * 4 + w;
    if (d >= N) return;
    int start = (int)row[d], end = (int)row[d + 1];
    int h = lane >> 4;                 // head for this lane's channel pair
    float adh = a_dst[d * HEADS + h];

    float den = 0.f, acc0 = 0.f, acc1 = 0.f;
    int e = start;
    // unroll x4: batch the index loads, then 8 independent gathers in flight
    for (; e + 4 <= end; e += 4) {
        int s0 = srcs[e], s1 = srcs[e + 1], s2 = srcs[e + 2], s3 = srcs[e + 3];
        float as0 = a_src[s0 * HEADS + h];
        float as1 = a_src[s1 * HEADS + h];
        float as2 = a_src[s2 * HEADS + h];
        float as3 = a_src[s3 * HEADS + h];
        unsigned int u0 = xhb[(size_t)s0 * 64 + lane];
        unsigned int u1 = xhb[(size_t)s1 * 64 + lane];
        unsigned int u2 = xhb[(size_t)s2 * 64 + lane];
        unsigned int u3 = xhb[(size_t)s3 * 64 + lane];
        float al0 = as0 + adh; al0 = (al0 >= 0.f) ? al0 : NEG_SLOPE * al0;
        float al1 = as1 + adh; al1 = (al1 >= 0.f) ? al1 : NEG_SLOPE * al1;
        float al2 = as2 + adh; al2 = (al2 >= 0.f) ? al2 : NEG_SLOPE * al2;
        float al3 = as3 + adh; al3 = (al3 >= 0.f) ? al3 : NEG_SLOPE * al3;
        float p0 = __expf(al0), p1 = __expf(al1), p2 = __expf(al2), p3 = __expf(al3);
        den += (p0 + p1) + (p2 + p3);
        acc0 += p0 * __uint_as_float(u0 << 16);
        acc1 += p0 * __uint_as_float(u0 & 0xFFFF0000u);
        acc0 += p1 * __uint_as_float(u1 << 16);
        acc1 += p1 * __uint_as_float(u1 & 0xFFFF0000u);
        acc0 += p2 * __uint_as_float(u2 << 16);
        acc1 += p2 * __uint_as_float(u2 & 0xFFFF0000u);
        acc0 += p3 * __uint_as_float(u3 << 16);
        acc1 += p3 * __uint_as_float(u3 & 0xFFFF0000u);
    }
    for (; e < end; ++e) {
        int s = srcs[e];
        float as = a_src[s * HEADS + h];
        unsigned int u = xhb[(size_t)s * 64 + lane];
        float al = as + adh; al = (al >= 0.f) ? al : NEG_SLOPE * al;
        float p = __expf(al);
        den += p;
        acc0 += p * __uint_as_float(u << 16);
        acc1 += p * __uint_as_float(u & 0xFFFF0000u);
    }
    float inv = 1.0f / den;
    float2 o; o.x = acc0 * inv; o.y = acc1 * inv;
    ((float2*)aggN)[(size_t)d * 64 + lane] = o;
}

// ---------- K4: bias+residual+LN2 + MFMA FFN + residual (16 nodes / 256 thr) ----------
// strides chosen so word-stride % 32 in {4,16}: all LDS accesses <= 2-way
#define SRST 132   // shres row stride (fp32 words), 132%32=4
#define ABST 136   // A_bf row stride (bf16) -> 68 words, 68%32=4
#define HST  264   // hid_bf row stride (bf16) -> 132 words, 132%32=4
__global__ __launch_bounds__(256) void k_final(
    const float* __restrict__ aggN,
    const float* __restrict__ x,
    const float* __restrict__ gat_b,
    const float* __restrict__ g2, const float* __restrict__ b2g,
    const unsigned short* __restrict__ wp1, const float* __restrict__ bb1,
    const unsigned short* __restrict__ wp2, const float* __restrict__ bb2,
    float* __restrict__ out, int N)
{
    __shared__ float shres[NPB * SRST];                       // 8448 B
    __shared__ __align__(16) unsigned short A_bf[NPB * ABST]; // 4352 B
    __shared__ __align__(16) unsigned short hid_bf[NPB * HST];// 8448 B
    int t = threadIdx.x;
    int w = t >> 6, lane = t & 63;
    int quad = lane >> 4, l15 = lane & 15;
    int nbase = blockIdx.x * NPB;

    // ---- Phase A: o+bias+residual, LN2 -> A_bf (bf16), shres (fp32) ----
#pragma unroll
    for (int i = 0; i < 4; ++i) {
        int nn = w * 4 + i;
        int n = nbase + nn;
        float h0 = 0.f, h1 = 0.f;
        if (n < N) {
            h0 = aggN[n * DIN + lane]      + gat_b[lane]      + x[n * DIN + lane];
            h1 = aggN[n * DIN + 64 + lane] + gat_b[64 + lane] + x[n * DIN + 64 + lane];
        }
        float mean = wave_allsum(h0 + h1) * (1.0f / DIN);
        float d0 = h0 - mean, d1 = h1 - mean;
        float var = wave_allsum(d0 * d0 + d1 * d1) * (1.0f / DIN);
        float rstd = rsqrtf(var + LN_EPS);
        shres[nn * SRST + lane]      = h0;
        shres[nn * SRST + 64 + lane] = h1;
        A_bf[nn * ABST + lane]      = f2bf(d0 * rstd * g2[lane]      + b2g[lane]);
        A_bf[nn * ABST + 64 + lane] = f2bf(d1 * rstd * g2[64 + lane] + b2g[64 + lane]);
    }
    __syncthreads();

    // ---- Phase B: FFN1 (16x256 = A[16x128] @ w1[128x256]) + GELU -> hid_bf ----
    {
        int arow = l15 * ABST;
        bf16x8 afrag[4];
#pragma unroll
        for (int ks = 0; ks < 4; ++ks)
            afrag[ks] = *(const bf16x8*)&A_bf[arow + ks * 32 + quad * 8];
#pragma unroll
        for (int nt = 0; nt < 4; ++nt) {
            int tile = w * 4 + nt;
            f32x4 acc = {0.f, 0.f, 0.f, 0.f};
#pragma unroll
            for (int ks = 0; ks < 4; ++ks) {
                bf16x8 bfrag = *(const bf16x8*)&wp1[(((tile * 4 + ks) * 64 + lane) << 3)];
                acc = __builtin_amdgcn_mfma_f32_16x16x32_bf16(afrag[ks], bfrag, acc, 0, 0, 0);
            }
            int col = tile * 16 + l15;
            float bias = bb1[col];
#pragma unroll
            for (int reg = 0; reg < 4; ++reg) {
                int m_local = quad * 4 + reg;
                float a = acc[reg] + bias;
                float g = 0.5f * a * (1.0f + erff(a * 0.70710678118654752f));
                hid_bf[m_local * HST + col] = f2bf(g);
            }
        }
    }
    __syncthreads();

    // ---- Phase C: FFN2 (16x128 = hid[16x256] @ w2[256x128]) + residual ----
    {
        int arow = l15 * HST;
        bf16x8 afrag[8];
#pragma unroll
        for (int ks = 0; ks < 8; ++ks)
            afrag[ks] = *(const bf16x8*)&hid_bf[arow + ks * 32 + quad * 8];
#pragma unroll
        for (int nt = 0; nt < 2; ++nt) {
            int tile = w * 2 + nt;
            f32x4 acc = {0.f, 0.f, 0.f, 0.f};
#pragma unroll
            for (int ks = 0; ks < 8; ++ks) {
                bf16x8 bfrag = *(const bf16x8*)&wp2[(((tile * 8 + ks) * 64 + lane) << 3)];
                acc = __builtin_amdgcn_mfma_f32_16x16x32_bf16(afrag[ks], bfrag, acc, 0, 0, 0);
            }
            int j = tile * 16 + l15;
            float bias = bb2[j];
#pragma unroll
            for (int reg = 0; reg < 4; ++reg) {
                int m_local = quad * 4 + reg;
                int n = nbase + m_local;
                if (n < N)
                    out[(size_t)n * DIN + j] = shres[m_local * SRST + j] + acc[reg] + bias;
            }
        }
    }
}

extern "C" void kernel_launch(void* const* d_in, const int* in_sizes, int n_in,
                              void* d_out, int out_size, void* d_ws, size_t ws_size,
                              hipStream_t stream) {
    const float* x       = (const float*)d_in[0];
    const int*   ei      = (const int*)d_in[1];
    const float* ln1_g   = (const float*)d_in[2];
    const float* ln1_b   = (const float*)d_in[3];
    const float* W       = (const float*)d_in[4];
    const float* att_src = (const float*)d_in[5];
    const float* att_dst = (const float*)d_in[6];
    const float* gat_b   = (const float*)d_in[7];
    const float* ln2_g   = (const float*)d_in[8];
    const float* ln2_b   = (const float*)d_in[9];
    const float* w1      = (const float*)d_in[10];
    const float* b1      = (const float*)d_in[11];
    const float* w2      = (const float*)d_in[12];
    const float* b2      = (const float*)d_in[13];
    float* out = (float*)d_out;

    const int N = in_sizes[0] / DIN;
    const int E = in_sizes[1] / 2;
    const int Et = E + N;
    const int Nper = (N + 7) / 8;

    // workspace layout:
    //   u16 wp1[32768] | u16 wp2[32768]           (16B-aligned at ws start)
    //   u32 cnt[N] (zeroed) | u32 row[N+1] | u32 pos[N] | u32 bsum[256] | u32 boff[256]
    //   int srcs[Et] | u16 xhb[N*128] | f32 a_src[N*4] | f32 a_dst[N*4] | f32 aggN[N*128]
    unsigned short* wp1 = (unsigned short*)d_ws;
    unsigned short* wp2 = wp1 + 32768;
    unsigned int* cnt  = (unsigned int*)(wp2 + 32768);
    unsigned int* row  = cnt + N;
    unsigned int* pos  = row + N + 1;
    unsigned int* bsum = pos + N;
    unsigned int* boff = bsum + 256;
    int*           srcs = (int*)(boff + 256);
    unsigned short* xhb = (unsigned short*)(srcs + Et);
    float*        a_src = (float*)(xhb + (size_t)N * DIN);
    float*        a_dst = a_src + (size_t)N * HEADS;
    float*        aggN  = a_dst + (size_t)N * HEADS;

    hipMemsetAsync(cnt, 0, (size_t)N * sizeof(unsigned int), stream);

    k_pack<<<256, 256, 0, stream>>>(w1, w2, wp1, wp2);

    int nblocks = (N + NB - 1) / NB;
    k_ln_proj<<<nblocks, 256, 0, stream>>>(x, ln1_g, ln1_b, W, att_src, att_dst, xhb, a_src, a_dst, N);

    int cblocks = (Et + CS - 1) / CS;
    int nb2 = (N + 255) / 256;   // must be <= 256 (N <= 65536)
    k_hist<<<cblocks * 8, 256, 0, stream>>>(ei, cnt, E, N, Nper);
    k_partsum<<<nb2, 256, 0, stream>>>(cnt, bsum, N);
    k_scanb<<<1, 256, 0, stream>>>(bsum, boff, row, nb2, N, Et);
    k_scanw<<<nb2, 256, 0, stream>>>(cnt, boff, row, pos, N);
    k_scatter<<<cblocks * 8, 256, 0, stream>>>(ei, pos, srcs, E, N, Nper);

    int ablocks = (N + 3) / 4;
    k_agg<<<ablocks, 256, 0, stream>>>(row, srcs, a_src, a_dst, (const unsigned int*)xhb, aggN, N);

    int nblocks4 = (N + NPB - 1) / NPB;
    k_final<<<nblocks4, 256, 0, stream>>>(aggN, x, gat_b, ln2_g, ln2_b, wp1, b1, wp2, b2, out, N);
}

// Round 9
// 277.235 us; speedup vs baseline: 4.1909x; 1.1072x over previous
//
#include <hip/hip_runtime.h>

#define DIN 128
#define HEADS 4
#define CPH 32
#define NEG_SLOPE 0.2f
#define LN_EPS 1e-5f
#define NPB 16  // nodes per block in K1/K4 (MFMA)
#define CS 4096 // edges per chunk in hist/scatter

typedef short bf16x8 __attribute__((ext_vector_type(8)));
typedef float f32x4 __attribute__((ext_vector_type(4)));

__device__ __forceinline__ float wave_allsum(float v) {
#pragma unroll
    for (int off = 32; off > 0; off >>= 1) v += __shfl_down(v, off, 64);
    return __shfl(v, 0, 64);
}

// round-to-nearest-even fp32 -> bf16 bits
__device__ __forceinline__ unsigned short f2bf(float f) {
    unsigned int b = __float_as_uint(f);
    b += 0x7FFFu + ((b >> 16) & 1u);
    return (unsigned short)(b >> 16);
}
__device__ __forceinline__ float bf2f(unsigned short u) {
    return __uint_as_float(((unsigned int)u) << 16);
}

// LDS row strides (shorts): 136 shorts = 68 words, 68%32=4 -> <=2-way conflicts
#define ABST 136
#define HST  264   // 132 words, %32=4
#define SRST 132   // fp32 words, %32=4

// ---------- K1: LN1 + MFMA projection + attention logits (16 nodes / 256 thr) ----------
__global__ __launch_bounds__(256) void k_ln_proj(
    const float* __restrict__ x,
    const float* __restrict__ g1, const float* __restrict__ b1,
    const unsigned short* __restrict__ wpW,
    const float* __restrict__ att_src, const float* __restrict__ att_dst,
    unsigned short* __restrict__ xhb, float* __restrict__ a_src, float* __restrict__ a_dst, int N)
{
    __shared__ __align__(16) unsigned short A_bf[NPB * ABST];  // LN1 out, bf16
    __shared__ __align__(16) unsigned short sxh[NPB * ABST];   // projected, bf16
    int t = threadIdx.x;
    int w = t >> 6, lane = t & 63;
    int quad = lane >> 4, l15 = lane & 15;
    int nbase = blockIdx.x * NPB;

    // ---- Phase A: LN1 -> A_bf ----
#pragma unroll
    for (int i = 0; i < 4; ++i) {
        int nn = w * 4 + i;
        int n = nbase + nn;
        float x0 = 0.f, x1 = 0.f;
        if (n < N) { x0 = x[n * DIN + lane]; x1 = x[n * DIN + 64 + lane]; }
        float mean = wave_allsum(x0 + x1) * (1.0f / DIN);
        float d0 = x0 - mean, d1 = x1 - mean;
        float var = wave_allsum(d0 * d0 + d1 * d1) * (1.0f / DIN);
        float rstd = rsqrtf(var + LN_EPS);
        A_bf[nn * ABST + lane]      = f2bf(d0 * rstd * g1[lane]      + b1[lane]);
        A_bf[nn * ABST + 64 + lane] = f2bf(d1 * rstd * g1[64 + lane] + b1[64 + lane]);
    }
    __syncthreads();

    // ---- Phase B: MFMA projection A[16x128] @ W[128x128] -> sxh ----
    {
        int arow = l15 * ABST;
        bf16x8 afrag[4];
#pragma unroll
        for (int ks = 0; ks < 4; ++ks)
            afrag[ks] = *(const bf16x8*)&A_bf[arow + ks * 32 + quad * 8];
#pragma unroll
        for (int nt = 0; nt < 2; ++nt) {
            int tile = w * 2 + nt;
            f32x4 acc = {0.f, 0.f, 0.f, 0.f};
#pragma unroll
            for (int ks = 0; ks < 4; ++ks) {
                bf16x8 bfrag = *(const bf16x8*)&wpW[(((tile * 4 + ks) * 64 + lane) << 3)];
                acc = __builtin_amdgcn_mfma_f32_16x16x32_bf16(afrag[ks], bfrag, acc, 0, 0, 0);
            }
            int col = tile * 16 + l15;
#pragma unroll
            for (int reg = 0; reg < 4; ++reg)
                sxh[(quad * 4 + reg) * ABST + col] = f2bf(acc[reg]);
        }
    }
    __syncthreads();

    // ---- Phase C: coalesced store of xh (bf16) ----
    {
        int node = t >> 4, off = (t & 15) * 8;
        int n = nbase + node;
        if (n < N)
            *(uint4*)&xhb[(size_t)n * DIN + off] = *(const uint4*)&sxh[node * ABST + off];
    }

    // ---- Phase D: attention logits from sxh ----
    {
        int node = w * 4 + (lane >> 4);          // 0..15
        int h = (lane >> 2) & 3, sub = lane & 3;
        float s1 = 0.f, s2 = 0.f;
#pragma unroll
        for (int i = 0; i < 8; ++i) {
            int c = h * CPH + sub * 8 + i;
            float v = bf2f(sxh[node * ABST + c]);
            s1 += v * att_src[c];
            s2 += v * att_dst[c];
        }
        s1 += __shfl_down(s1, 1, 64); s2 += __shfl_down(s2, 1, 64);
        s1 += __shfl_down(s1, 2, 64); s2 += __shfl_down(s2, 2, 64);
        int n = nbase + node;
        if (sub == 0 && n < N) {
            a_src[n * HEADS + h] = s1;
            a_dst[n * HEADS + h] = s2;
        }
    }
}

// ---------- pack w1/w2/W into bf16 MFMA B-fragment order ----------
__global__ __launch_bounds__(256) void k_pack(
    const float* __restrict__ w1, const float* __restrict__ w2, const float* __restrict__ W,
    unsigned short* __restrict__ wp1, unsigned short* __restrict__ wp2,
    unsigned short* __restrict__ wpW)
{
    int idx = blockIdx.x * 256 + threadIdx.x;
    if (idx < 32768) {
        int j = idx & 7, lane = (idx >> 3) & 63, tk = idx >> 9;
        int ks = tk & 3, tile = tk >> 2;
        int k = ks * 32 + ((lane >> 4) << 3) + j;
        int n = tile * 16 + (lane & 15);
        wp1[idx] = f2bf(w1[k * 256 + n]);
    } else if (idx < 65536) {
        int i2 = idx - 32768;
        int j = i2 & 7, lane = (i2 >> 3) & 63, tk = i2 >> 9;
        int ks = tk & 7, tile = tk >> 3;
        int k = ks * 32 + ((lane >> 4) << 3) + j;
        int n = tile * 16 + (lane & 15);
        wp2[i2] = f2bf(w2[k * 128 + n]);
    } else {
        int i3 = idx - 65536;
        int j = i3 & 7, lane = (i3 >> 3) & 63, tk = i3 >> 9;
        int ks = tk & 3, tile = tk >> 2;
        int k = ks * 32 + ((lane >> 4) << 3) + j;
        int n = tile * 16 + (lane & 15);
        wpW[i3] = f2bf(W[k * 128 + n]);
    }
}

// ---------- CSR build: histogram, XCD-partitioned by dst range ----------
__global__ __launch_bounds__(256) void k_hist(
    const int* __restrict__ ei, unsigned int* __restrict__ cnt, int E, int N, int Nper)
{
    int xcd = blockIdx.x & 7, chunk = blockIdx.x >> 3;
    int lo = xcd * Nper, hi = min(lo + Nper, N);
    int Et = E + N;
    int base = chunk * CS + threadIdx.x;
#pragma unroll
    for (int i = 0; i < CS / 256; ++i) {
        int e = base + i * 256;
        if (e >= Et) break;
        int d = (e < E) ? ei[E + e] : (e - E);
        if (d >= lo && d < hi) atomicAdd(&cnt[d], 1u);
    }
}

// ---------- CSR build: per-block partial sums ----------
__global__ __launch_bounds__(256) void k_partsum(
    const unsigned int* __restrict__ cnt, unsigned int* __restrict__ bsum, int N)
{
    __shared__ unsigned int sm[4];
    int t = threadIdx.x;
    int i = blockIdx.x * 256 + t;
    unsigned int v = (i < N) ? cnt[i] : 0u;
#pragma unroll
    for (int off = 32; off > 0; off >>= 1) v += (unsigned int)__shfl_down((int)v, off, 64);
    if ((t & 63) == 0) sm[t >> 6] = v;
    __syncthreads();
    if (t == 0) bsum[blockIdx.x] = sm[0] + sm[1] + sm[2] + sm[3];
}

// ---------- CSR build: scan of block sums ----------
__global__ __launch_bounds__(256) void k_scanb(
    const unsigned int* __restrict__ bsum, unsigned int* __restrict__ boff,
    unsigned int* __restrict__ row, int nb2, int N, int Et)
{
    __shared__ unsigned int sm[256];
    int t = threadIdx.x;
    unsigned int v = (t < nb2) ? bsum[t] : 0u;
    sm[t] = v;
    __syncthreads();
#pragma unroll
    for (int off = 1; off < 256; off <<= 1) {
        unsigned int a = (t >= off) ? sm[t - off] : 0u;
        __syncthreads();
        sm[t] += a;
        __syncthreads();
    }
    if (t < nb2) boff[t] = sm[t] - v;
    if (t == 0) row[N] = (unsigned int)Et;
}

// ---------- CSR build: per-element exclusive scan ----------
__global__ __launch_bounds__(256) void k_scanw(
    const unsigned int* __restrict__ cnt, const unsigned int* __restrict__ boff,
    unsigned int* __restrict__ row, unsigned int* __restrict__ pos, int N)
{
    __shared__ unsigned int sm[256];
    int t = threadIdx.x;
    int i = blockIdx.x * 256 + t;
    unsigned int v = (i < N) ? cnt[i] : 0u;
    sm[t] = v;
    __syncthreads();
#pragma unroll
    for (int off = 1; off < 256; off <<= 1) {
        unsigned int a = (t >= off) ? sm[t - off] : 0u;
        __syncthreads();
        sm[t] += a;
        __syncthreads();
    }
    if (i < N) {
        unsigned int o = boff[blockIdx.x] + sm[t] - v;
        row[i] = o;
        pos[i] = o;
    }
}

// ---------- CSR build: scatter src indices, XCD-partitioned by dst range ----------
__global__ __launch_bounds__(256) void k_scatter(
    const int* __restrict__ ei, unsigned int* __restrict__ pos,
    int* __restrict__ srcs, int E, int N, int Nper)
{
    int xcd = blockIdx.x & 7, chunk = blockIdx.x >> 3;
    int lo = xcd * Nper, hi = min(lo + Nper, N);
    int Et = E + N;
    int base = chunk * CS + threadIdx.x;
#pragma unroll
    for (int i = 0; i < CS / 256; ++i) {
        int e = base + i * 256;
        if (e >= Et) break;
        int d = (e < E) ? ei[E + e] : (e - E);
        if (d >= lo && d < hi) {
            int s = (e < E) ? ei[e] : d;
            unsigned int p = atomicAdd(&pos[d], 1u);
            srcs[p] = s;
        }
    }
}

// ---------- K3: segment softmax + aggregation, one wave per dst ----------
__global__ __launch_bounds__(256) void k_agg(
    const unsigned int* __restrict__ row, const int* __restrict__ srcs,
    const float* __restrict__ a_src, const float* __restrict__ a_dst,
    const unsigned int* __restrict__ xhb,   // packed bf16 pairs, N*64 words
    float* __restrict__ aggN, int N)
{
    int w = threadIdx.x >> 6, lane = threadIdx.x & 63;
    int d = blockIdx.x * 4 + w;
    if (d >= N) return;
    int start = (int)row[d], end = (int)row[d + 1];
    int h = lane >> 4;
    float adh = a_dst[d * HEADS + h];

    float den = 0.f, acc0 = 0.f, acc1 = 0.f;
    int e = start;
    for (; e + 4 <= end; e += 4) {
        int s0 = srcs[e], s1 = srcs[e + 1], s2 = srcs[e + 2], s3 = srcs[e + 3];
        float as0 = a_src[s0 * HEADS + h];
        float as1 = a_src[s1 * HEADS + h];
        float as2 = a_src[s2 * HEADS + h];
        float as3 = a_src[s3 * HEADS + h];
        unsigned int u0 = xhb[(size_t)s0 * 64 + lane];
        unsigned int u1 = xhb[(size_t)s1 * 64 + lane];
        unsigned int u2 = xhb[(size_t)s2 * 64 + lane];
        unsigned int u3 = xhb[(size_t)s3 * 64 + lane];
        float al0 = as0 + adh; al0 = (al0 >= 0.f) ? al0 : NEG_SLOPE * al0;
        float al1 = as1 + adh; al1 = (al1 >= 0.f) ? al1 : NEG_SLOPE * al1;
        float al2 = as2 + adh; al2 = (al2 >= 0.f) ? al2 : NEG_SLOPE * al2;
        float al3 = as3 + adh; al3 = (al3 >= 0.f) ? al3 : NEG_SLOPE * al3;
        float p0 = __expf(al0), p1 = __expf(al1), p2 = __expf(al2), p3 = __expf(al3);
        den += (p0 + p1) + (p2 + p3);
        acc0 += p0 * __uint_as_float(u0 << 16);
        acc1 += p0 * __uint_as_float(u0 & 0xFFFF0000u);
        acc0 += p1 * __uint_as_float(u1 << 16);
        acc1 += p1 * __uint_as_float(u1 & 0xFFFF0000u);
        acc0 += p2 * __uint_as_float(u2 << 16);
        acc1 += p2 * __uint_as_float(u2 & 0xFFFF0000u);
        acc0 += p3 * __uint_as_float(u3 << 16);
        acc1 += p3 * __uint_as_float(u3 & 0xFFFF0000u);
    }
    for (; e < end; ++e) {
        int s = srcs[e];
        float as = a_src[s * HEADS + h];
        unsigned int u = xhb[(size_t)s * 64 + lane];
        float al = as + adh; al = (al >= 0.f) ? al : NEG_SLOPE * al;
        float p = __expf(al);
        den += p;
        acc0 += p * __uint_as_float(u << 16);
        acc1 += p * __uint_as_float(u & 0xFFFF0000u);
    }
    float inv = 1.0f / den;
    float2 o; o.x = acc0 * inv; o.y = acc1 * inv;
    ((float2*)aggN)[(size_t)d * 64 + lane] = o;
}

// ---------- K4: bias+residual+LN2 + MFMA FFN + residual (16 nodes / 256 thr) ----------
__global__ __launch_bounds__(256) void k_final(
    const float* __restrict__ aggN,
    const float* __restrict__ x,
    const float* __restrict__ gat_b,
    const float* __restrict__ g2, const float* __restrict__ b2g,
    const unsigned short* __restrict__ wp1, const float* __restrict__ bb1,
    const unsigned short* __restrict__ wp2, const float* __restrict__ bb2,
    float* __restrict__ out, int N)
{
    __shared__ float shres[NPB * SRST];
    __shared__ __align__(16) unsigned short A_bf[NPB * ABST];
    __shared__ __align__(16) unsigned short hid_bf[NPB * HST];
    int t = threadIdx.x;
    int w = t >> 6, lane = t & 63;
    int quad = lane >> 4, l15 = lane & 15;
    int nbase = blockIdx.x * NPB;

#pragma unroll
    for (int i = 0; i < 4; ++i) {
        int nn = w * 4 + i;
        int n = nbase + nn;
        float h0 = 0.f, h1 = 0.f;
        if (n < N) {
            h0 = aggN[n * DIN + lane]      + gat_b[lane]      + x[n * DIN + lane];
            h1 = aggN[n * DIN + 64 + lane] + gat_b[64 + lane] + x[n * DIN + 64 + lane];
        }
        float mean = wave_allsum(h0 + h1) * (1.0f / DIN);
        float d0 = h0 - mean, d1 = h1 - mean;
        float var = wave_allsum(d0 * d0 + d1 * d1) * (1.0f / DIN);
        float rstd = rsqrtf(var + LN_EPS);
        shres[nn * SRST + lane]      = h0;
        shres[nn * SRST + 64 + lane] = h1;
        A_bf[nn * ABST + lane]      = f2bf(d0 * rstd * g2[lane]      + b2g[lane]);
        A_bf[nn * ABST + 64 + lane] = f2bf(d1 * rstd * g2[64 + lane] + b2g[64 + lane]);
    }
    __syncthreads();

    // FFN1 + GELU -> hid_bf
    {
        int arow = l15 * ABST;
        bf16x8 afrag[4];
#pragma unroll
        for (int ks = 0; ks < 4; ++ks)
            afrag[ks] = *(const bf16x8*)&A_bf[arow + ks * 32 + quad * 8];
#pragma unroll
        for (int nt = 0; nt < 4; ++nt) {
            int tile = w * 4 + nt;
            f32x4 acc = {0.f, 0.f, 0.f, 0.f};
#pragma unroll
            for (int ks = 0; ks < 4; ++ks) {
                bf16x8 bfrag = *(const bf16x8*)&wp1[(((tile * 4 + ks) * 64 + lane) << 3)];
                acc = __builtin_amdgcn_mfma_f32_16x16x32_bf16(afrag[ks], bfrag, acc, 0, 0, 0);
            }
            int col = tile * 16 + l15;
            float bias = bb1[col];
#pragma unroll
            for (int reg = 0; reg < 4; ++reg) {
                int m_local = quad * 4 + reg;
                float a = acc[reg] + bias;
                float g = 0.5f * a * (1.0f + erff(a * 0.70710678118654752f));
                hid_bf[m_local * HST + col] = f2bf(g);
            }
        }
    }
    __syncthreads();

    // FFN2 + residual
    {
        int arow = l15 * HST;
        bf16x8 afrag[8];
#pragma unroll
        for (int ks = 0; ks < 8; ++ks)
            afrag[ks] = *(const bf16x8*)&hid_bf[arow + ks * 32 + quad * 8];
#pragma unroll
        for (int nt = 0; nt < 2; ++nt) {
            int tile = w * 2 + nt;
            f32x4 acc = {0.f, 0.f, 0.f, 0.f};
#pragma unroll
            for (int ks = 0; ks < 8; ++ks) {
                bf16x8 bfrag = *(const bf16x8*)&wp2[(((tile * 8 + ks) * 64 + lane) << 3)];
                acc = __builtin_amdgcn_mfma_f32_16x16x32_bf16(afrag[ks], bfrag, acc, 0, 0, 0);
            }
            int j = tile * 16 + l15;
            float bias = bb2[j];
#pragma unroll
            for (int reg = 0; reg < 4; ++reg) {
                int m_local = quad * 4 + reg;
                int n = nbase + m_local;
                if (n < N)
                    out[(size_t)n * DIN + j] = shres[m_local * SRST + j] + acc[reg] + bias;
            }
        }
    }
}

extern "C" void kernel_launch(void* const* d_in, const int* in_sizes, int n_in,
                              void* d_out, int out_size, void* d_ws, size_t ws_size,
                              hipStream_t stream) {
    const float* x       = (const float*)d_in[0];
    const int*   ei      = (const int*)d_in[1];
    const float* ln1_g   = (const float*)d_in[2];
    const float* ln1_b   = (const float*)d_in[3];
    const float* W       = (const float*)d_in[4];
    const float* att_src = (const float*)d_in[5];
    const float* att_dst = (const float*)d_in[6];
    const float* gat_b   = (const float*)d_in[7];
    const float* ln2_g   = (const float*)d_in[8];
    const float* ln2_b   = (const float*)d_in[9];
    const float* w1      = (const float*)d_in[10];
    const float* b1      = (const float*)d_in[11];
    const float* w2      = (const float*)d_in[12];
    const float* b2      = (const float*)d_in[13];
    float* out = (float*)d_out;

    const int N = in_sizes[0] / DIN;
    const int E = in_sizes[1] / 2;
    const int Et = E + N;
    const int Nper = (N + 7) / 8;

    // workspace layout:
    //   u16 wp1[32768] | u16 wp2[32768] | u16 wpW[16384]
    //   u32 cnt[N] (zeroed) | u32 row[N+1] | u32 pos[N] | u32 bsum[256] | u32 boff[256]
    //   int srcs[Et] | u16 xhb[N*128] | f32 a_src[N*4] | f32 a_dst[N*4] | f32 aggN[N*128]
    unsigned short* wp1 = (unsigned short*)d_ws;
    unsigned short* wp2 = wp1 + 32768;
    unsigned short* wpW = wp2 + 32768;
    unsigned int* cnt  = (unsigned int*)(wpW + 16384);
    unsigned int* row  = cnt + N;
    unsigned int* pos  = row + N + 1;
    unsigned int* bsum = pos + N;
    unsigned int* boff = bsum + 256;
    int*           srcs = (int*)(boff + 256);
    unsigned short* xhb = (unsigned short*)(srcs + Et);
    float*        a_src = (float*)(xhb + (size_t)N * DIN);
    float*        a_dst = a_src + (size_t)N * HEADS;
    float*        aggN  = a_dst + (size_t)N * HEADS;

    hipMemsetAsync(cnt, 0, (size_t)N * sizeof(unsigned int), stream);

    k_pack<<<320, 256, 0, stream>>>(w1, w2, W, wp1, wp2, wpW);

    int nblocks = (N + NPB - 1) / NPB;
    k_ln_proj<<<nblocks, 256, 0, stream>>>(x, ln1_g, ln1_b, wpW, att_src, att_dst, xhb, a_src, a_dst, N);

    int cblocks = (Et + CS - 1) / CS;
    int nb2 = (N + 255) / 256;   // must be <= 256 (N <= 65536)
    k_hist<<<cblocks * 8, 256, 0, stream>>>(ei, cnt, E, N, Nper);
    k_partsum<<<nb2, 256, 0, stream>>>(cnt, bsum, N);
    k_scanb<<<1, 256, 0, stream>>>(bsum, boff, row, nb2, N, Et);
    k_scanw<<<nb2, 256, 0, stream>>>(cnt, boff, row, pos, N);
    k_scatter<<<cblocks * 8, 256, 0, stream>>>(ei, pos, srcs, E, N, Nper);

    int ablocks = (N + 3) / 4;
    k_agg<<<ablocks, 256, 0, stream>>>(row, srcs, a_src, a_dst, (const unsigned int*)xhb, aggN, N);

    k_final<<<nblocks, 256, 0, stream>>>(aggN, x, gat_b, ln2_g, ln2_b, wp1, b1, wp2, b2, out, N);
}

// Round 10
// 273.022 us; speedup vs baseline: 4.2556x; 1.0154x over previous
//
#include <hip/hip_runtime.h>

#define DIN 128
#define HEADS 4
#define CPH 32
#define NEG_SLOPE 0.2f
#define LN_EPS 1e-5f
#define NPB 16  // nodes per block in K1/K4 (MFMA)
#define CS 4096 // edges per chunk in hist/scatter

typedef short bf16x8 __attribute__((ext_vector_type(8)));
typedef float f32x4 __attribute__((ext_vector_type(4)));

__device__ __forceinline__ float wave_allsum(float v) {
#pragma unroll
    for (int off = 32; off > 0; off >>= 1) v += __shfl_down(v, off, 64);
    return __shfl(v, 0, 64);
}

// round-to-nearest-even fp32 -> bf16 bits
__device__ __forceinline__ unsigned short f2bf(float f) {
    unsigned int b = __float_as_uint(f);
    b += 0x7FFFu + ((b >> 16) & 1u);
    return (unsigned short)(b >> 16);
}
__device__ __forceinline__ float bf2f(unsigned short u) {
    return __uint_as_float(((unsigned int)u) << 16);
}

// LDS row strides (shorts): 136 shorts = 68 words, 68%32=4 -> <=2-way conflicts
#define ABST 136
#define HST  264   // 132 words, %32=4
#define SRST 132   // fp32 words, %32=4

// ---------- K1: LN1 + MFMA projection + attention logits (16 nodes / 256 thr) ----------
__global__ __launch_bounds__(256) void k_ln_proj(
    const float* __restrict__ x,
    const float* __restrict__ g1, const float* __restrict__ b1,
    const unsigned short* __restrict__ wpW,
    const float* __restrict__ att_src, const float* __restrict__ att_dst,
    unsigned short* __restrict__ xhb, float* __restrict__ a_src, float* __restrict__ a_dst, int N)
{
    __shared__ __align__(16) unsigned short A_bf[NPB * ABST];  // LN1 out, bf16
    __shared__ __align__(16) unsigned short sxh[NPB * ABST];   // projected, bf16
    int t = threadIdx.x;
    int w = t >> 6, lane = t & 63;
    int quad = lane >> 4, l15 = lane & 15;
    int nbase = blockIdx.x * NPB;

    // ---- Phase A: LN1 -> A_bf ----
#pragma unroll
    for (int i = 0; i < 4; ++i) {
        int nn = w * 4 + i;
        int n = nbase + nn;
        float x0 = 0.f, x1 = 0.f;
        if (n < N) { x0 = x[n * DIN + lane]; x1 = x[n * DIN + 64 + lane]; }
        float mean = wave_allsum(x0 + x1) * (1.0f / DIN);
        float d0 = x0 - mean, d1 = x1 - mean;
        float var = wave_allsum(d0 * d0 + d1 * d1) * (1.0f / DIN);
        float rstd = rsqrtf(var + LN_EPS);
        A_bf[nn * ABST + lane]      = f2bf(d0 * rstd * g1[lane]      + b1[lane]);
        A_bf[nn * ABST + 64 + lane] = f2bf(d1 * rstd * g1[64 + lane] + b1[64 + lane]);
    }
    __syncthreads();

    // ---- Phase B: MFMA projection A[16x128] @ W[128x128] -> sxh ----
    {
        int arow = l15 * ABST;
        bf16x8 afrag[4];
#pragma unroll
        for (int ks = 0; ks < 4; ++ks)
            afrag[ks] = *(const bf16x8*)&A_bf[arow + ks * 32 + quad * 8];
#pragma unroll
        for (int nt = 0; nt < 2; ++nt) {
            int tile = w * 2 + nt;
            f32x4 acc = {0.f, 0.f, 0.f, 0.f};
#pragma unroll
            for (int ks = 0; ks < 4; ++ks) {
                bf16x8 bfrag = *(const bf16x8*)&wpW[(((tile * 4 + ks) * 64 + lane) << 3)];
                acc = __builtin_amdgcn_mfma_f32_16x16x32_bf16(afrag[ks], bfrag, acc, 0, 0, 0);
            }
            int col = tile * 16 + l15;
#pragma unroll
            for (int reg = 0; reg < 4; ++reg)
                sxh[(quad * 4 + reg) * ABST + col] = f2bf(acc[reg]);
        }
    }
    __syncthreads();

    // ---- Phase C: coalesced store of xh (bf16) ----
    {
        int node = t >> 4, off = (t & 15) * 8;
        int n = nbase + node;
        if (n < N)
            *(uint4*)&xhb[(size_t)n * DIN + off] = *(const uint4*)&sxh[node * ABST + off];
    }

    // ---- Phase D: attention logits from sxh ----
    {
        int node = w * 4 + (lane >> 4);          // 0..15
        int h = (lane >> 2) & 3, sub = lane & 3;
        float s1 = 0.f, s2 = 0.f;
#pragma unroll
        for (int i = 0; i < 8; ++i) {
            int c = h * CPH + sub * 8 + i;
            float v = bf2f(sxh[node * ABST + c]);
            s1 += v * att_src[c];
            s2 += v * att_dst[c];
        }
        s1 += __shfl_down(s1, 1, 64); s2 += __shfl_down(s2, 1, 64);
        s1 += __shfl_down(s1, 2, 64); s2 += __shfl_down(s2, 2, 64);
        int n = nbase + node;
        if (sub == 0 && n < N) {
            a_src[n * HEADS + h] = s1;
            a_dst[n * HEADS + h] = s2;
        }
    }
}

// ---------- pack w1/w2/W into bf16 MFMA B-fragment order ----------
__global__ __launch_bounds__(256) void k_pack(
    const float* __restrict__ w1, const float* __restrict__ w2, const float* __restrict__ W,
    unsigned short* __restrict__ wp1, unsigned short* __restrict__ wp2,
    unsigned short* __restrict__ wpW)
{
    int idx = blockIdx.x * 256 + threadIdx.x;
    if (idx < 32768) {
        int j = idx & 7, lane = (idx >> 3) & 63, tk = idx >> 9;
        int ks = tk & 3, tile = tk >> 2;
        int k = ks * 32 + ((lane >> 4) << 3) + j;
        int n = tile * 16 + (lane & 15);
        wp1[idx] = f2bf(w1[k * 256 + n]);
    } else if (idx < 65536) {
        int i2 = idx - 32768;
        int j = i2 & 7, lane = (i2 >> 3) & 63, tk = i2 >> 9;
        int ks = tk & 7, tile = tk >> 3;
        int k = ks * 32 + ((lane >> 4) << 3) + j;
        int n = tile * 16 + (lane & 15);
        wp2[i2] = f2bf(w2[k * 128 + n]);
    } else {
        int i3 = idx - 65536;
        int j = i3 & 7, lane = (i3 >> 3) & 63, tk = i3 >> 9;
        int ks = tk & 3, tile = tk >> 2;
        int k = ks * 32 + ((lane >> 4) << 3) + j;
        int n = tile * 16 + (lane & 15);
        wpW[i3] = f2bf(W[k * 128 + n]);
    }
}

// ---------- CSR build: histogram, XCD-partitioned by dst range ----------
__global__ __launch_bounds__(256) void k_hist(
    const int* __restrict__ ei, unsigned int* __restrict__ cnt, int E, int N, int Nper)
{
    int xcd = blockIdx.x & 7, chunk = blockIdx.x >> 3;
    int lo = xcd * Nper, hi = min(lo + Nper, N);
    int Et = E + N;
    int base = chunk * CS + threadIdx.x;
#pragma unroll
    for (int i = 0; i < CS / 256; ++i) {
        int e = base + i * 256;
        if (e >= Et) break;
        int d = (e < E) ? ei[E + e] : (e - E);
        if (d >= lo && d < hi) atomicAdd(&cnt[d], 1u);
    }
}

// ---------- CSR build: per-block partial sums ----------
__global__ __launch_bounds__(256) void k_partsum(
    const unsigned int* __restrict__ cnt, unsigned int* __restrict__ bsum, int N)
{
    __shared__ unsigned int sm[4];
    int t = threadIdx.x;
    int i = blockIdx.x * 256 + t;
    unsigned int v = (i < N) ? cnt[i] : 0u;
#pragma unroll
    for (int off = 32; off > 0; off >>= 1) v += (unsigned int)__shfl_down((int)v, off, 64);
    if ((t & 63) == 0) sm[t >> 6] = v;
    __syncthreads();
    if (t == 0) bsum[blockIdx.x] = sm[0] + sm[1] + sm[2] + sm[3];
}

// ---------- CSR build: scan of block sums ----------
__global__ __launch_bounds__(256) void k_scanb(
    const unsigned int* __restrict__ bsum, unsigned int* __restrict__ boff,
    unsigned int* __restrict__ row, int nb2, int N, int Et)
{
    __shared__ unsigned int sm[256];
    int t = threadIdx.x;
    unsigned int v = (t < nb2) ? bsum[t] : 0u;
    sm[t] = v;
    __syncthreads();
#pragma unroll
    for (int off = 1; off < 256; off <<= 1) {
        unsigned int a = (t >= off) ? sm[t - off] : 0u;
        __syncthreads();
        sm[t] += a;
        __syncthreads();
    }
    if (t < nb2) boff[t] = sm[t] - v;
    if (t == 0) row[N] = (unsigned int)Et;
}

// ---------- CSR build: per-element exclusive scan ----------
__global__ __launch_bounds__(256) void k_scanw(
    const unsigned int* __restrict__ cnt, const unsigned int* __restrict__ boff,
    unsigned int* __restrict__ row, unsigned int* __restrict__ pos, int N)
{
    __shared__ unsigned int sm[256];
    int t = threadIdx.x;
    int i = blockIdx.x * 256 + t;
    unsigned int v = (i < N) ? cnt[i] : 0u;
    sm[t] = v;
    __syncthreads();
#pragma unroll
    for (int off = 1; off < 256; off <<= 1) {
        unsigned int a = (t >= off) ? sm[t - off] : 0u;
        __syncthreads();
        sm[t] += a;
        __syncthreads();
    }
    if (i < N) {
        unsigned int o = boff[blockIdx.x] + sm[t] - v;
        row[i] = o;
        pos[i] = o;
    }
}

// ---------- CSR build: scatter src indices, XCD-partitioned by dst range ----------
__global__ __launch_bounds__(256) void k_scatter(
    const int* __restrict__ ei, unsigned int* __restrict__ pos,
    int* __restrict__ srcs, int E, int N, int Nper)
{
    int xcd = blockIdx.x & 7, chunk = blockIdx.x >> 3;
    int lo = xcd * Nper, hi = min(lo + Nper, N);
    int Et = E + N;
    int base = chunk * CS + threadIdx.x;
#pragma unroll
    for (int i = 0; i < CS / 256; ++i) {
        int e = base + i * 256;
        if (e >= Et) break;
        int d = (e < E) ? ei[E + e] : (e - E);
        if (d >= lo && d < hi) {
            int s = (e < E) ? ei[e] : d;
            unsigned int p = atomicAdd(&pos[d], 1u);
            srcs[p] = s;
        }
    }
}

// ---------- K4: fused segment-softmax aggregation + bias+residual+LN2 + MFMA FFN
//             + residual (16 nodes / 256 thr) ----------
__global__ __launch_bounds__(256) void k_agg_final(
    const unsigned int* __restrict__ row, const int* __restrict__ srcs,
    const float* __restrict__ a_src, const float* __restrict__ a_dst,
    const unsigned int* __restrict__ xhb,   // packed bf16 pairs, N*64 words
    const float* __restrict__ x,
    const float* __restrict__ gat_b,
    const float* __restrict__ g2, const float* __restrict__ b2g,
    const unsigned short* __restrict__ wp1, const float* __restrict__ bb1,
    const unsigned short* __restrict__ wp2, const float* __restrict__ bb2,
    float* __restrict__ out, int N)
{
    __shared__ float shres[NPB * SRST];
    __shared__ __align__(16) unsigned short A_bf[NPB * ABST];
    __shared__ __align__(16) unsigned short hid_bf[NPB * HST];
    int t = threadIdx.x;
    int w = t >> 6, lane = t & 63;
    int quad = lane >> 4, l15 = lane & 15;
    int nbase = blockIdx.x * NPB;

    // ---- Phase 0: segment softmax + aggregation. Wave w: nodes w*4..w*4+3.
    // Lane covers channels 2*lane, 2*lane+1; head = lane>>4. Result -> shres (LDS).
#pragma unroll
    for (int i = 0; i < 4; ++i) {
        int nn = w * 4 + i;
        int d = nbase + nn;
        float o0 = 0.f, o1 = 0.f;
        if (d < N) {
            int start = (int)row[d], end = (int)row[d + 1];
            int h = lane >> 4;
            float adh = a_dst[d * HEADS + h];
            float den = 0.f, acc0 = 0.f, acc1 = 0.f;
            int e = start;
            for (; e + 4 <= end; e += 4) {
                int s0 = srcs[e], s1 = srcs[e + 1], s2 = srcs[e + 2], s3 = srcs[e + 3];
                float as0 = a_src[s0 * HEADS + h];
                float as1 = a_src[s1 * HEADS + h];
                float as2 = a_src[s2 * HEADS + h];
                float as3 = a_src[s3 * HEADS + h];
                unsigned int u0 = xhb[(size_t)s0 * 64 + lane];
                unsigned int u1 = xhb[(size_t)s1 * 64 + lane];
                unsigned int u2 = xhb[(size_t)s2 * 64 + lane];
                unsigned int u3 = xhb[(size_t)s3 * 64 + lane];
                float al0 = as0 + adh; al0 = (al0 >= 0.f) ? al0 : NEG_SLOPE * al0;
                float al1 = as1 + adh; al1 = (al1 >= 0.f) ? al1 : NEG_SLOPE * al1;
                float al2 = as2 + adh; al2 = (al2 >= 0.f) ? al2 : NEG_SLOPE * al2;
                float al3 = as3 + adh; al3 = (al3 >= 0.f) ? al3 : NEG_SLOPE * al3;
                float p0 = __expf(al0), p1 = __expf(al1), p2 = __expf(al2), p3 = __expf(al3);
                den += (p0 + p1) + (p2 + p3);
                acc0 += p0 * __uint_as_float(u0 << 16);
                acc1 += p0 * __uint_as_float(u0 & 0xFFFF0000u);
                acc0 += p1 * __uint_as_float(u1 << 16);
                acc1 += p1 * __uint_as_float(u1 & 0xFFFF0000u);
                acc0 += p2 * __uint_as_float(u2 << 16);
                acc1 += p2 * __uint_as_float(u2 & 0xFFFF0000u);
                acc0 += p3 * __uint_as_float(u3 << 16);
                acc1 += p3 * __uint_as_float(u3 & 0xFFFF0000u);
            }
            for (; e < end; ++e) {
                int s = srcs[e];
                float as = a_src[s * HEADS + h];
                unsigned int u = xhb[(size_t)s * 64 + lane];
                float al = as + adh; al = (al >= 0.f) ? al : NEG_SLOPE * al;
                float p = __expf(al);
                den += p;
                acc0 += p * __uint_as_float(u << 16);
                acc1 += p * __uint_as_float(u & 0xFFFF0000u);
            }
            float inv = 1.0f / den;
            o0 = acc0 * inv; o1 = acc1 * inv;
        }
        shres[nn * SRST + 2 * lane]     = o0;
        shres[nn * SRST + 2 * lane + 1] = o1;
    }
    // same-wave LDS write->read below (wave w only touches its own nodes): no barrier needed

    // ---- Phase A: o+bias+residual, LN2 -> A_bf (bf16), shres (fp32, overwritten) ----
#pragma unroll
    for (int i = 0; i < 4; ++i) {
        int nn = w * 4 + i;
        int n = nbase + nn;
        float h0 = 0.f, h1 = 0.f;
        if (n < N) {
            h0 = shres[nn * SRST + lane]      + gat_b[lane]      + x[n * DIN + lane];
            h1 = shres[nn * SRST + 64 + lane] + gat_b[64 + lane] + x[n * DIN + 64 + lane];
        }
        float mean = wave_allsum(h0 + h1) * (1.0f / DIN);
        float d0 = h0 - mean, d1 = h1 - mean;
        float var = wave_allsum(d0 * d0 + d1 * d1) * (1.0f / DIN);
        float rstd = rsqrtf(var + LN_EPS);
        shres[nn * SRST + lane]      = h0;
        shres[nn * SRST + 64 + lane] = h1;
        A_bf[nn * ABST + lane]      = f2bf(d0 * rstd * g2[lane]      + b2g[lane]);
        A_bf[nn * ABST + 64 + lane] = f2bf(d1 * rstd * g2[64 + lane] + b2g[64 + lane]);
    }
    __syncthreads();

    // ---- Phase B: FFN1 (16x256) + GELU -> hid_bf ----
    {
        int arow = l15 * ABST;
        bf16x8 afrag[4];
#pragma unroll
        for (int ks = 0; ks < 4; ++ks)
            afrag[ks] = *(const bf16x8*)&A_bf[arow + ks * 32 + quad * 8];
#pragma unroll
        for (int nt = 0; nt < 4; ++nt) {
            int tile = w * 4 + nt;
            f32x4 acc = {0.f, 0.f, 0.f, 0.f};
#pragma unroll
            for (int ks = 0; ks < 4; ++ks) {
                bf16x8 bfrag = *(const bf16x8*)&wp1[(((tile * 4 + ks) * 64 + lane) << 3)];
                acc = __builtin_amdgcn_mfma_f32_16x16x32_bf16(afrag[ks], bfrag, acc, 0, 0, 0);
            }
            int col = tile * 16 + l15;
            float bias = bb1[col];
#pragma unroll
            for (int reg = 0; reg < 4; ++reg) {
                int m_local = quad * 4 + reg;
                float a = acc[reg] + bias;
                float g = 0.5f * a * (1.0f + erff(a * 0.70710678118654752f));
                hid_bf[m_local * HST + col] = f2bf(g);
            }
        }
    }
    __syncthreads();

    // ---- Phase C: FFN2 (16x128) + residual ----
    {
        int arow = l15 * HST;
        bf16x8 afrag[8];
#pragma unroll
        for (int ks = 0; ks < 8; ++ks)
            afrag[ks] = *(const bf16x8*)&hid_bf[arow + ks * 32 + quad * 8];
#pragma unroll
        for (int nt = 0; nt < 2; ++nt) {
            int tile = w * 2 + nt;
            f32x4 acc = {0.f, 0.f, 0.f, 0.f};
#pragma unroll
            for (int ks = 0; ks < 8; ++ks) {
                bf16x8 bfrag = *(const bf16x8*)&wp2[(((tile * 8 + ks) * 64 + lane) << 3)];
                acc = __builtin_amdgcn_mfma_f32_16x16x32_bf16(afrag[ks], bfrag, acc, 0, 0, 0);
            }
            int j = tile * 16 + l15;
            float bias = bb2[j];
#pragma unroll
            for (int reg = 0; reg < 4; ++reg) {
                int m_local = quad * 4 + reg;
                int n = nbase + m_local;
                if (n < N)
                    out[(size_t)n * DIN + j] = shres[m_local * SRST + j] + acc[reg] + bias;
            }
        }
    }
}

extern "C" void kernel_launch(void* const* d_in, const int* in_sizes, int n_in,
                              void* d_out, int out_size, void* d_ws, size_t ws_size,
                              hipStream_t stream) {
    const float* x       = (const float*)d_in[0];
    const int*   ei      = (const int*)d_in[1];
    const float* ln1_g   = (const float*)d_in[2];
    const float* ln1_b   = (const float*)d_in[3];
    const float* W       = (const float*)d_in[4];
    const float* att_src = (const float*)d_in[5];
    const float* att_dst = (const float*)d_in[6];
    const float* gat_b   = (const float*)d_in[7];
    const float* ln2_g   = (const float*)d_in[8];
    const float* ln2_b   = (const float*)d_in[9];
    const float* w1      = (const float*)d_in[10];
    const float* b1      = (const float*)d_in[11];
    const float* w2      = (const float*)d_in[12];
    const float* b2      = (const float*)d_in[13];
    float* out = (float*)d_out;

    const int N = in_sizes[0] / DIN;
    const int E = in_sizes[1] / 2;
    const int Et = E + N;
    const int Nper = (N + 7) / 8;

    // workspace layout:
    //   u16 wp1[32768] | u16 wp2[32768] | u16 wpW[16384]
    //   u32 cnt[N] (zeroed) | u32 row[N+1] | u32 pos[N] | u32 bsum[256] | u32 boff[256]
    //   int srcs[Et] | u16 xhb[N*128] | f32 a_src[N*4] | f32 a_dst[N*4]
    unsigned short* wp1 = (unsigned short*)d_ws;
    unsigned short* wp2 = wp1 + 32768;
    unsigned short* wpW = wp2 + 32768;
    unsigned int* cnt  = (unsigned int*)(wpW + 16384);
    unsigned int* row  = cnt + N;
    unsigned int* pos  = row + N + 1;
    unsigned int* bsum = pos + N;
    unsigned int* boff = bsum + 256;
    int*           srcs = (int*)(boff + 256);
    unsigned short* xhb = (unsigned short*)(srcs + Et);
    float*        a_src = (float*)(xhb + (size_t)N * DIN);
    float*        a_dst = a_src + (size_t)N * HEADS;

    hipMemsetAsync(cnt, 0, (size_t)N * sizeof(unsigned int), stream);

    k_pack<<<320, 256, 0, stream>>>(w1, w2, W, wp1, wp2, wpW);

    int nblocks = (N + NPB - 1) / NPB;
    k_ln_proj<<<nblocks, 256, 0, stream>>>(x, ln1_g, ln1_b, wpW, att_src, att_dst, xhb, a_src, a_dst, N);

    int cblocks = (Et + CS - 1) / CS;
    int nb2 = (N + 255) / 256;   // must be <= 256 (N <= 65536)
    k_hist<<<cblocks * 8, 256, 0, stream>>>(ei, cnt, E, N, Nper);
    k_partsum<<<nb2, 256, 0, stream>>>(cnt, bsum, N);
    k_scanb<<<1, 256, 0, stream>>>(bsum, boff, row, nb2, N, Et);
    k_scanw<<<nb2, 256, 0, stream>>>(cnt, boff, row, pos, N);
    k_scatter<<<cblocks * 8, 256, 0, stream>>>(ei, pos, srcs, E, N, Nper);

    k_agg_final<<<nblocks, 256, 0, stream>>>(row, srcs, a_src, a_dst, (const unsigned int*)xhb,
                                             x, gat_b, ln2_g, ln2_b, wp1, b1, wp2, b2, out, N);
}

// Round 12
// 271.160 us; speedup vs baseline: 4.2848x; 1.0069x over previous
//
#include <hip/hip_runtime.h>

#define DIN 128
#define HEADS 4
#define CPH 32
#define NEG_SLOPE 0.2f
#define LN_EPS 1e-5f
#define NPB 16  // nodes per block in K1/K4 (MFMA)
#define CS 4096 // edges per chunk in hist/scatter

typedef short bf16x8 __attribute__((ext_vector_type(8)));
typedef float f32x4 __attribute__((ext_vector_type(4)));
typedef float f32x2 __attribute__((ext_vector_type(2)));

__device__ __forceinline__ float wave_allsum(float v) {
#pragma unroll
    for (int off = 32; off > 0; off >>= 1) v += __shfl_down(v, off, 64);
    return __shfl(v, 0, 64);
}

// round-to-nearest-even fp32 -> bf16 bits
__device__ __forceinline__ unsigned short f2bf(float f) {
    unsigned int b = __float_as_uint(f);
    b += 0x7FFFu + ((b >> 16) & 1u);
    return (unsigned short)(b >> 16);
}
__device__ __forceinline__ float bf2f(unsigned short u) {
    return __uint_as_float(((unsigned int)u) << 16);
}

// LDS row strides (shorts): 136 shorts = 68 words, 68%32=4 -> <=2-way conflicts
#define ABST 136
#define HST  264   // 132 words, %32=4
#define SRST 132   // fp32 words, %32=4

// ---------- K1: LN1 + MFMA projection + attention logits (16 nodes / 256 thr) ----------
__global__ __launch_bounds__(256) void k_ln_proj(
    const float* __restrict__ x,
    const float* __restrict__ g1, const float* __restrict__ b1,
    const unsigned short* __restrict__ wpW,
    const float* __restrict__ att_src, const float* __restrict__ att_dst,
    unsigned short* __restrict__ xhb, float* __restrict__ a_src, float* __restrict__ a_dst, int N)
{
    __shared__ __align__(16) unsigned short A_bf[NPB * ABST];  // LN1 out, bf16
    __shared__ __align__(16) unsigned short sxh[NPB * ABST];   // projected, bf16
    int t = threadIdx.x;
    int w = t >> 6, lane = t & 63;
    int quad = lane >> 4, l15 = lane & 15;
    int nbase = blockIdx.x * NPB;

    // ---- Phase A: LN1 -> A_bf ----
#pragma unroll
    for (int i = 0; i < 4; ++i) {
        int nn = w * 4 + i;
        int n = nbase + nn;
        float x0 = 0.f, x1 = 0.f;
        if (n < N) { x0 = x[n * DIN + lane]; x1 = x[n * DIN + 64 + lane]; }
        float mean = wave_allsum(x0 + x1) * (1.0f / DIN);
        float d0 = x0 - mean, d1 = x1 - mean;
        float var = wave_allsum(d0 * d0 + d1 * d1) * (1.0f / DIN);
        float rstd = rsqrtf(var + LN_EPS);
        A_bf[nn * ABST + lane]      = f2bf(d0 * rstd * g1[lane]      + b1[lane]);
        A_bf[nn * ABST + 64 + lane] = f2bf(d1 * rstd * g1[64 + lane] + b1[64 + lane]);
    }
    __syncthreads();

    // ---- Phase B: MFMA projection A[16x128] @ W[128x128] -> sxh ----
    {
        int arow = l15 * ABST;
        bf16x8 afrag[4];
#pragma unroll
        for (int ks = 0; ks < 4; ++ks)
            afrag[ks] = *(const bf16x8*)&A_bf[arow + ks * 32 + quad * 8];
#pragma unroll
        for (int nt = 0; nt < 2; ++nt) {
            int tile = w * 2 + nt;
            f32x4 acc = {0.f, 0.f, 0.f, 0.f};
#pragma unroll
            for (int ks = 0; ks < 4; ++ks) {
                bf16x8 bfrag = *(const bf16x8*)&wpW[(((tile * 4 + ks) * 64 + lane) << 3)];
                acc = __builtin_amdgcn_mfma_f32_16x16x32_bf16(afrag[ks], bfrag, acc, 0, 0, 0);
            }
            int col = tile * 16 + l15;
#pragma unroll
            for (int reg = 0; reg < 4; ++reg)
                sxh[(quad * 4 + reg) * ABST + col] = f2bf(acc[reg]);
        }
    }
    __syncthreads();

    // ---- Phase C: coalesced store of xh (bf16) ----
    {
        int node = t >> 4, off = (t & 15) * 8;
        int n = nbase + node;
        if (n < N)
            *(uint4*)&xhb[(size_t)n * DIN + off] = *(const uint4*)&sxh[node * ABST + off];
    }

    // ---- Phase D: attention logits from sxh (bf16) ----
    {
        int node = w * 4 + (lane >> 4);          // 0..15
        int h = (lane >> 2) & 3, sub = lane & 3;
        float s1 = 0.f, s2 = 0.f;
#pragma unroll
        for (int i = 0; i < 8; ++i) {
            int c = h * CPH + sub * 8 + i;
            float v = bf2f(sxh[node * ABST + c]);
            s1 += v * att_src[c];
            s2 += v * att_dst[c];
        }
        s1 += __shfl_down(s1, 1, 64); s2 += __shfl_down(s2, 1, 64);
        s1 += __shfl_down(s1, 2, 64); s2 += __shfl_down(s2, 2, 64);
        int n = nbase + node;
        if (sub == 0 && n < N) {
            a_src[n * HEADS + h] = s1;
            a_dst[n * HEADS + h] = s2;
        }
    }
}

// ---------- pack w1/w2/W into bf16 MFMA B-fragment order ----------
__global__ __launch_bounds__(256) void k_pack(
    const float* __restrict__ w1, const float* __restrict__ w2, const float* __restrict__ W,
    unsigned short* __restrict__ wp1, unsigned short* __restrict__ wp2,
    unsigned short* __restrict__ wpW)
{
    int idx = blockIdx.x * 256 + threadIdx.x;
    if (idx < 32768) {
        int j = idx & 7, lane = (idx >> 3) & 63, tk = idx >> 9;
        int ks = tk & 3, tile = tk >> 2;
        int k = ks * 32 + ((lane >> 4) << 3) + j;
        int n = tile * 16 + (lane & 15);
        wp1[idx] = f2bf(w1[k * 256 + n]);
    } else if (idx < 65536) {
        int i2 = idx - 32768;
        int j = i2 & 7, lane = (i2 >> 3) & 63, tk = i2 >> 9;
        int ks = tk & 7, tile = tk >> 3;
        int k = ks * 32 + ((lane >> 4) << 3) + j;
        int n = tile * 16 + (lane & 15);
        wp2[i2] = f2bf(w2[k * 128 + n]);
    } else {
        int i3 = idx - 65536;
        int j = i3 & 7, lane = (i3 >> 3) & 63, tk = i3 >> 9;
        int ks = tk & 3, tile = tk >> 2;
        int k = ks * 32 + ((lane >> 4) << 3) + j;
        int n = tile * 16 + (lane & 15);
        wpW[i3] = f2bf(W[k * 128 + n]);
    }
}

// ---------- CSR build: histogram, XCD-partitioned by dst range ----------
__global__ __launch_bounds__(256) void k_hist(
    const int* __restrict__ ei, unsigned int* __restrict__ cnt, int E, int N, int Nper)
{
    int xcd = blockIdx.x & 7, chunk = blockIdx.x >> 3;
    int lo = xcd * Nper, hi = min(lo + Nper, N);
    int Et = E + N;
    int base = chunk * CS + threadIdx.x;
#pragma unroll
    for (int i = 0; i < CS / 256; ++i) {
        int e = base + i * 256;
        if (e >= Et) break;
        int d = (e < E) ? ei[E + e] : (e - E);
        if (d >= lo && d < hi) atomicAdd(&cnt[d], 1u);
    }
}

// ---------- CSR build: per-block partial sums ----------
__global__ __launch_bounds__(256) void k_partsum(
    const unsigned int* __restrict__ cnt, unsigned int* __restrict__ bsum, int N)
{
    __shared__ unsigned int sm[4];
    int t = threadIdx.x;
    int i = blockIdx.x * 256 + t;
    unsigned int v = (i < N) ? cnt[i] : 0u;
#pragma unroll
    for (int off = 32; off > 0; off >>= 1) v += (unsigned int)__shfl_down((int)v, off, 64);
    if ((t & 63) == 0) sm[t >> 6] = v;
    __syncthreads();
    if (t == 0) bsum[blockIdx.x] = sm[0] + sm[1] + sm[2] + sm[3];
}

// ---------- CSR build: scan of block sums ----------
__global__ __launch_bounds__(256) void k_scanb(
    const unsigned int* __restrict__ bsum, unsigned int* __restrict__ boff,
    unsigned int* __restrict__ row, int nb2, int N, int Et)
{
    __shared__ unsigned int sm[256];
    int t = threadIdx.x;
    unsigned int v = (t < nb2) ? bsum[t] : 0u;
    sm[t] = v;
    __syncthreads();
#pragma unroll
    for (int off = 1; off < 256; off <<= 1) {
        unsigned int a = (t >= off) ? sm[t - off] : 0u;
        __syncthreads();
        sm[t] += a;
        __syncthreads();
    }
    if (t < nb2) boff[t] = sm[t] - v;
    if (t == 0) row[N] = (unsigned int)Et;
}

// ---------- CSR build: per-element exclusive scan ----------
__global__ __launch_bounds__(256) void k_scanw(
    const unsigned int* __restrict__ cnt, const unsigned int* __restrict__ boff,
    unsigned int* __restrict__ row, unsigned int* __restrict__ pos, int N)
{
    __shared__ unsigned int sm[256];
    int t = threadIdx.x;
    int i = blockIdx.x * 256 + t;
    unsigned int v = (i < N) ? cnt[i] : 0u;
    sm[t] = v;
    __syncthreads();
#pragma unroll
    for (int off = 1; off < 256; off <<= 1) {
        unsigned int a = (t >= off) ? sm[t - off] : 0u;
        __syncthreads();
        sm[t] += a;
        __syncthreads();
    }
    if (i < N) {
        unsigned int o = boff[blockIdx.x] + sm[t] - v;
        row[i] = o;
        pos[i] = o;
    }
}

// ---------- CSR build: scatter src indices, XCD-partitioned by dst range ----------
__global__ __launch_bounds__(256) void k_scatter(
    const int* __restrict__ ei, unsigned int* __restrict__ pos,
    int* __restrict__ srcs, int E, int N, int Nper)
{
    int xcd = blockIdx.x & 7, chunk = blockIdx.x >> 3;
    int lo = xcd * Nper, hi = min(lo + Nper, N);
    int Et = E + N;
    int base = chunk * CS + threadIdx.x;
#pragma unroll
    for (int i = 0; i < CS / 256; ++i) {
        int e = base + i * 256;
        if (e >= Et) break;
        int d = (e < E) ? ei[E + e] : (e - E);
        if (d >= lo && d < hi) {
            int s = (e < E) ? ei[e] : d;
            unsigned int p = atomicAdd(&pos[d], 1u);
            srcs[p] = s;
        }
    }
}

// ---------- K4: fused segment-softmax aggregation + bias+residual+LN2 + MFMA FFN
//             + residual (16 nodes / 256 thr) ----------
__global__ __launch_bounds__(256) void k_agg_final(
    const unsigned int* __restrict__ row, const int* __restrict__ srcs,
    const float* __restrict__ a_src, const float* __restrict__ a_dst,
    const unsigned int* __restrict__ xhb,   // packed bf16 pairs, N*64 words
    const float* __restrict__ x,
    const float* __restrict__ gat_b,
    const float* __restrict__ g2, const float* __restrict__ b2g,
    const unsigned short* __restrict__ wp1, const float* __restrict__ bb1,
    const unsigned short* __restrict__ wp2, const float* __restrict__ bb2,
    float* __restrict__ out, int N)
{
    __shared__ float shres[NPB * SRST];
    __shared__ __align__(16) unsigned short A_bf[NPB * ABST];
    __shared__ __align__(16) unsigned short hid_bf[NPB * HST];
    int t = threadIdx.x;
    int w = t >> 6, lane = t & 63;
    int quad = lane >> 4, l15 = lane & 15;
    int nbase = blockIdx.x * NPB;
    int h = lane >> 4;   // head for this lane's channel pair

    // per-wave channel-pair constants (channels 2*lane, 2*lane+1)
    f32x2 gbp, g2p, b2p;
    {
        const f32x2* gb2 = (const f32x2*)gat_b;
        const f32x2* gg2 = (const f32x2*)g2;
        const f32x2* bb2v = (const f32x2*)b2g;
        gbp = gb2[lane]; g2p = gg2[lane]; b2p = bb2v[lane];
    }

    // ---- Phase 0+A: per node: softmax-agg (regs) -> +bias+residual -> LN2 ----
#pragma unroll
    for (int i = 0; i < 4; ++i) {
        int nn = w * 4 + i;
        int d = nbase + nn;
        float o0 = 0.f, o1 = 0.f;
        if (d < N) {
            int start = (int)row[d], end = (int)row[d + 1];
            float adh = a_dst[d * HEADS + h];
            float den = 0.f;
            int e = start;
            for (; e + 4 <= end; e += 4) {
                int s0 = srcs[e], s1 = srcs[e + 1], s2 = srcs[e + 2], s3 = srcs[e + 3];
                float as0 = a_src[s0 * HEADS + h];
                float as1 = a_src[s1 * HEADS + h];
                float as2 = a_src[s2 * HEADS + h];
                float as3 = a_src[s3 * HEADS + h];
                unsigned int u0 = xhb[(size_t)s0 * 64 + lane];
                unsigned int u1 = xhb[(size_t)s1 * 64 + lane];
                unsigned int u2 = xhb[(size_t)s2 * 64 + lane];
                unsigned int u3 = xhb[(size_t)s3 * 64 + lane];
                float al0 = as0 + adh; al0 = (al0 >= 0.f) ? al0 : NEG_SLOPE * al0;
                float al1 = as1 + adh; al1 = (al1 >= 0.f) ? al1 : NEG_SLOPE * al1;
                float al2 = as2 + adh; al2 = (al2 >= 0.f) ? al2 : NEG_SLOPE * al2;
                float al3 = as3 + adh; al3 = (al3 >= 0.f) ? al3 : NEG_SLOPE * al3;
                float p0 = __expf(al0), p1 = __expf(al1), p2 = __expf(al2), p3 = __expf(al3);
                den += (p0 + p1) + (p2 + p3);
                o0 += p0 * __uint_as_float(u0 << 16);
                o1 += p0 * __uint_as_float(u0 & 0xFFFF0000u);
                o0 += p1 * __uint_as_float(u1 << 16);
                o1 += p1 * __uint_as_float(u1 & 0xFFFF0000u);
                o0 += p2 * __uint_as_float(u2 << 16);
                o1 += p2 * __uint_as_float(u2 & 0xFFFF0000u);
                o0 += p3 * __uint_as_float(u3 << 16);
                o1 += p3 * __uint_as_float(u3 & 0xFFFF0000u);
            }
            for (; e < end; ++e) {
                int s = srcs[e];
                float as = a_src[s * HEADS + h];
                unsigned int u = xhb[(size_t)s * 64 + lane];
                float al = as + adh; al = (al >= 0.f) ? al : NEG_SLOPE * al;
                float p = __expf(al);
                den += p;
                o0 += p * __uint_as_float(u << 16);
                o1 += p * __uint_as_float(u & 0xFFFF0000u);
            }
            float inv = 1.0f / den;
            o0 *= inv; o1 *= inv;
        }

        // bias + residual (channel-pair layout), LN2
        float h0 = 0.f, h1 = 0.f;
        if (d < N) {
            f32x2 xv = ((const f32x2*)(x + (size_t)d * DIN))[lane];
            h0 = o0 + gbp.x + xv.x;
            h1 = o1 + gbp.y + xv.y;
        }
        float mean = wave_allsum(h0 + h1) * (1.0f / DIN);
        float d0 = h0 - mean, d1 = h1 - mean;
        float var = wave_allsum(d0 * d0 + d1 * d1) * (1.0f / DIN);
        float rstd = rsqrtf(var + LN_EPS);
        // shres as float2 (stride-1 pairs), A_bf as packed uint (stride-1 words)
        f32x2 hres; hres.x = h0; hres.y = h1;
        ((f32x2*)&shres[nn * SRST])[lane] = hres;
        unsigned int apk = (unsigned int)f2bf(d0 * rstd * g2p.x + b2p.x)
                         | ((unsigned int)f2bf(d1 * rstd * g2p.y + b2p.y) << 16);
        ((unsigned int*)&A_bf[nn * ABST])[lane] = apk;
    }
    __syncthreads();

    // ---- Phase B: FFN1 (16x256) + GELU -> hid_bf ----
    {
        int arow = l15 * ABST;
        bf16x8 afrag[4];
#pragma unroll
        for (int ks = 0; ks < 4; ++ks)
            afrag[ks] = *(const bf16x8*)&A_bf[arow + ks * 32 + quad * 8];
#pragma unroll
        for (int nt = 0; nt < 4; ++nt) {
            int tile = w * 4 + nt;
            f32x4 acc = {0.f, 0.f, 0.f, 0.f};
#pragma unroll
            for (int ks = 0; ks < 4; ++ks) {
                bf16x8 bfrag = *(const bf16x8*)&wp1[(((tile * 4 + ks) * 64 + lane) << 3)];
                acc = __builtin_amdgcn_mfma_f32_16x16x32_bf16(afrag[ks], bfrag, acc, 0, 0, 0);
            }
            int col = tile * 16 + l15;
            float bias = bb1[col];
#pragma unroll
            for (int reg = 0; reg < 4; ++reg) {
                int m_local = quad * 4 + reg;
                float a = acc[reg] + bias;
                float g = 0.5f * a * (1.0f + erff(a * 0.70710678118654752f));
                hid_bf[m_local * HST + col] = f2bf(g);
            }
        }
    }
    __syncthreads();

    // ---- Phase C: FFN2 (16x128) + residual ----
    {
        int arow = l15 * HST;
        bf16x8 afrag[8];
#pragma unroll
        for (int ks = 0; ks < 8; ++ks)
            afrag[ks] = *(const bf16x8*)&hid_bf[arow + ks * 32 + quad * 8];
#pragma unroll
        for (int nt = 0; nt < 2; ++nt) {
            int tile = w * 2 + nt;
            f32x4 acc = {0.f, 0.f, 0.f, 0.f};
#pragma unroll
            for (int ks = 0; ks < 8; ++ks) {
                bf16x8 bfrag = *(const bf16x8*)&wp2[(((tile * 8 + ks) * 64 + lane) << 3)];
                acc = __builtin_amdgcn_mfma_f32_16x16x32_bf16(afrag[ks], bfrag, acc, 0, 0, 0);
            }
            int j = tile * 16 + l15;
            float bias = bb2[j];
#pragma unroll
            for (int reg = 0; reg < 4; ++reg) {
                int m_local = quad * 4 + reg;
                int n = nbase + m_local;
                if (n < N)
                    out[(size_t)n * DIN + j] = shres[m_local * SRST + j] + acc[reg] + bias;
            }
        }
    }
}

extern "C" void kernel_launch(void* const* d_in, const int* in_sizes, int n_in,
                              void* d_out, int out_size, void* d_ws, size_t ws_size,
                              hipStream_t stream) {
    const float* x       = (const float*)d_in[0];
    const int*   ei      = (const int*)d_in[1];
    const float* ln1_g   = (const float*)d_in[2];
    const float* ln1_b   = (const float*)d_in[3];
    const float* W       = (const float*)d_in[4];
    const float* att_src = (const float*)d_in[5];
    const float* att_dst = (const float*)d_in[6];
    const float* gat_b   = (const float*)d_in[7];
    const float* ln2_g   = (const float*)d_in[8];
    const float* ln2_b   = (const float*)d_in[9];
    const float* w1      = (const float*)d_in[10];
    const float* b1      = (const float*)d_in[11];
    const float* w2      = (const float*)d_in[12];
    const float* b2      = (const float*)d_in[13];
    float* out = (float*)d_out;

    const int N = in_sizes[0] / DIN;
    const int E = in_sizes[1] / 2;
    const int Et = E + N;
    const int Nper = (N + 7) / 8;

    // workspace layout:
    //   u16 wp1[32768] | u16 wp2[32768] | u16 wpW[16384]
    //   u32 cnt[N] (zeroed) | u32 row[N+1] | u32 pos[N] | u32 bsum[256] | u32 boff[256]
    //   int srcs[Et] | u16 xhb[N*128] | f32 a_src[N*4] | f32 a_dst[N*4]
    unsigned short* wp1 = (unsigned short*)d_ws;
    unsigned short* wp2 = wp1 + 32768;
    unsigned short* wpW = wp2 + 32768;
    unsigned int* cnt  = (unsigned int*)(wpW + 16384);
    unsigned int* row  = cnt + N;
    unsigned int* pos  = row + N + 1;
    unsigned int* bsum = pos + N;
    unsigned int* boff = bsum + 256;
    int*           srcs = (int*)(boff + 256);
    unsigned short* xhb = (unsigned short*)(srcs + Et);
    float*        a_src = (float*)(xhb + (size_t)N * DIN);
    float*        a_dst = a_src + (size_t)N * HEADS;

    hipMemsetAsync(cnt, 0, (size_t)N * sizeof(unsigned int), stream);

    k_pack<<<320, 256, 0, stream>>>(w1, w2, W, wp1, wp2, wpW);

    int nblocks = (N + NPB - 1) / NPB;
    k_ln_proj<<<nblocks, 256, 0, stream>>>(x, ln1_g, ln1_b, wpW, att_src, att_dst, xhb, a_src, a_dst, N);

    int cblocks = (Et + CS - 1) / CS;
    int nb2 = (N + 255) / 256;   // must be <= 256 (N <= 65536)
    k_hist<<<cblocks * 8, 256, 0, stream>>>(ei, cnt, E, N, Nper);
    k_partsum<<<nb2, 256, 0, stream>>>(cnt, bsum, N);
    k_scanb<<<1, 256, 0, stream>>>(bsum, boff, row, nb2, N, Et);
    k_scanw<<<nb2, 256, 0, stream>>>(cnt, boff, row, pos, N);
    k_scatter<<<cblocks * 8, 256, 0, stream>>>(ei, pos, srcs, E, N, Nper);

    k_agg_final<<<nblocks, 256, 0, stream>>>(row, srcs, a_src, a_dst, (const unsigned int*)xhb,
                                             x, gat_b, ln2_g, ln2_b, wp1, b1, wp2, b2, out, N);
}